// Round 1
// baseline (4845.925 us; speedup 1.0000x reference)
//
#include <hip/hip_runtime.h>
#include <math.h>

// ===========================================================================
// AlexCapsNet forward, fp32 throughout.
// ws layout (needs ~141.3 MB):
//   R0 = [0, 38.5MB)      : p1 / p2 / a4 / p3 / u / f1
//   R1 = [38.5MB, 141.3MB): a2 / a3 / a5 / pc / v / f2 ; fc2 partials at R1+16MB
// ===========================================================================

#define BATCH 512

// ---------------- conv1(1->96,3x3,p1) + relu + maxpool(3,2,1) fused --------
__global__ __launch_bounds__(256) void conv1_pool_kernel(
    const float* __restrict__ x, const float* __restrict__ w1,
    const float* __restrict__ b1, float* __restrict__ out)
{
    int idx = blockIdx.x * 256 + threadIdx.x;       // total = 512*96*14*14
    if (idx >= 512 * 96 * 14 * 14) return;
    int ow = idx % 14; int t1 = idx / 14;
    int oh = t1 % 14;  int t2 = t1 / 14;
    int oc = t2 % 96;  int n  = t2 / 96;
    const float* xi = x + n * 784;
    float w[9];
#pragma unroll
    for (int i = 0; i < 9; ++i) w[i] = w1[oc * 9 + i];
    float bias = b1[oc];
    float best = -3.4e38f;
#pragma unroll
    for (int dy = 0; dy < 3; ++dy) {
        int ph = oh * 2 - 1 + dy;
        if ((unsigned)ph >= 28u) continue;
#pragma unroll
        for (int dx = 0; dx < 3; ++dx) {
            int pw = ow * 2 - 1 + dx;
            if ((unsigned)pw >= 28u) continue;
            float s = bias;
#pragma unroll
            for (int ky = 0; ky < 3; ++ky) {
                int iy = ph - 1 + ky;
                if ((unsigned)iy >= 28u) continue;
#pragma unroll
                for (int kx = 0; kx < 3; ++kx) {
                    int ix = pw - 1 + kx;
                    if ((unsigned)ix >= 28u) continue;
                    s = fmaf(w[ky * 3 + kx], xi[iy * 28 + ix], s);
                }
            }
            s = fmaxf(s, 0.f);
            best = fmaxf(best, s);
        }
    }
    out[idx] = best;
}

// ---------------- generic maxpool -----------------------------------------
template<int C, int H, int W, int OH, int OW, int KS, int STR, int PADP>
__global__ __launch_bounds__(256) void maxpool_kernel(
    const float* __restrict__ in, float* __restrict__ out)
{
    constexpr int TOTAL = BATCH * C * OH * OW;
    int idx = blockIdx.x * 256 + threadIdx.x;
    if (idx >= TOTAL) return;
    int ow = idx % OW; int t1 = idx / OW;
    int oh = t1 % OH;  int t2 = t1 / OH;
    int c  = t2 % C;   int n  = t2 / C;
    const float* ip = in + (size_t)(n * C + c) * (H * W);
    float best = -3.4e38f;
#pragma unroll
    for (int dy = 0; dy < KS; ++dy) {
        int ih = oh * STR - PADP + dy;
        if ((unsigned)ih >= (unsigned)H) continue;
#pragma unroll
        for (int dx = 0; dx < KS; ++dx) {
            int iw = ow * STR - PADP + dx;
            if ((unsigned)iw >= (unsigned)W) continue;
            best = fmaxf(best, ip[ih * W + iw]);
        }
    }
    out[idx] = best;
}

// ---------------- implicit-GEMM conv (3x3 p1 or 2x2 p0), 128x64 tile -------
// C[m][j], m = oc (M = OC, tiled 128), j = n*OHW + p (N = 512*OHW, tiled 64),
// K = IC*KH*KH, chunked by 16. A = weights [OC][K] row-major.
template<int IC, int H, int W, int KH, int PAD, int OC, bool RELU>
__global__ __launch_bounds__(256) void conv_gemm(
    const float* __restrict__ in, const float* __restrict__ wt,
    const float* __restrict__ bias, float* __restrict__ out)
{
    constexpr int OH  = H + 2 * PAD - KH + 1;
    constexpr int OW  = W + 2 * PAD - KH + 1;
    constexpr int OHW = OH * OW;
    constexpr int K   = IC * KH * KH;
    static_assert(K % 16 == 0, "K chunking");

    const int t  = threadIdx.x;
    const int j0 = blockIdx.x << 6;
    const int m0 = blockIdx.y << 7;

    __shared__ __align__(16) float As[16 * 132];  // [k][m], stride 132
    __shared__ __align__(16) float Bs[16 * 64];   // [k][j]

    float acc[8][4];
#pragma unroll
    for (int a = 0; a < 8; ++a)
#pragma unroll
        for (int b = 0; b < 4; ++b) acc[a][b] = 0.f;

    // A loader: thread -> (row t>>2 [+64], 4 consecutive k at (t&3)*4)
    const int a_m = t >> 2;
    const int a_k = (t & 3) << 2;
    // B loader: thread -> column j0+(t&63), k rows (t>>6) + {0,4,8,12}
    const int b_j = t & 63;
    const int b_k = t >> 6;
    const int jg  = j0 + b_j;
    const int n_b = jg / OHW;
    const int p_b = jg - n_b * OHW;
    const int oh  = p_b / OW;
    const int ow  = p_b - oh * OW;
    const float* inb = in + (size_t)n_b * (IC * H * W);

    const int ms = (t >> 4) << 3;   // 16 m-subtiles of 8
    const int js = (t & 15) << 2;   // 16 j-subtiles of 4

    for (int kb0 = 0; kb0 < K; kb0 += 16) {
        // ---- stage A (weights) transposed into LDS ----
#pragma unroll
        for (int r = 0; r < 2; ++r) {
            int m = m0 + a_m + (r << 6);
            float4 av = *(const float4*)(wt + (size_t)m * K + kb0 + a_k);
            As[(a_k + 0) * 132 + a_m + (r << 6)] = av.x;
            As[(a_k + 1) * 132 + a_m + (r << 6)] = av.y;
            As[(a_k + 2) * 132 + a_m + (r << 6)] = av.z;
            As[(a_k + 3) * 132 + a_m + (r << 6)] = av.w;
        }
        // ---- stage B (im2col gather) ----
#pragma unroll
        for (int c = 0; c < 4; ++c) {
            int kk = b_k + (c << 2);
            int k  = kb0 + kk;
            int ic = k / (KH * KH);
            int rr = k - ic * (KH * KH);
            int kh = rr / KH;
            int kw = rr - kh * KH;
            int ih = oh + kh - PAD;
            int iw = ow + kw - PAD;
            float v = 0.f;
            if ((unsigned)ih < (unsigned)H && (unsigned)iw < (unsigned)W)
                v = inb[ic * (H * W) + ih * W + iw];
            Bs[(kk << 6) + b_j] = v;
        }
        __syncthreads();
        // ---- compute ----
#pragma unroll
        for (int kk = 0; kk < 16; ++kk) {
            float4 A0 = *(const float4*)&As[kk * 132 + ms];
            float4 A1 = *(const float4*)&As[kk * 132 + ms + 4];
            float4 B0 = *(const float4*)&Bs[(kk << 6) + js];
            float av[8] = {A0.x, A0.y, A0.z, A0.w, A1.x, A1.y, A1.z, A1.w};
            float bv[4] = {B0.x, B0.y, B0.z, B0.w};
#pragma unroll
            for (int mm = 0; mm < 8; ++mm)
#pragma unroll
                for (int jj = 0; jj < 4; ++jj)
                    acc[mm][jj] = fmaf(av[mm], bv[jj], acc[mm][jj]);
        }
        __syncthreads();
    }
    // ---- epilogue: bias (+relu), scatter to NCHW ----
    float bv8[8];
#pragma unroll
    for (int mm = 0; mm < 8; ++mm) bv8[mm] = bias[m0 + ms + mm];
#pragma unroll
    for (int jj = 0; jj < 4; ++jj) {
        int j = j0 + js + jj;
        int n = j / OHW;
        int p = j - n * OHW;
        float* op = out + (size_t)n * (OC * OHW) + p;
#pragma unroll
        for (int mm = 0; mm < 8; ++mm) {
            float v = acc[mm][jj] + bv8[mm];
            if (RELU) v = fmaxf(v, 0.f);
            op[(size_t)(m0 + ms + mm) * OHW] = v;
        }
    }
}

// ---------------- FC GEMM: out[m][j] = sum_k A[m][k]*Bw[j][k] --------------
// M = 512 (tile 128), N (tile 64), K chunked 16. Optional split-K via grid.z.
template<bool RELU>
__global__ __launch_bounds__(256) void fc_gemm(
    const float* __restrict__ A, const float* __restrict__ Bw,
    const float* __restrict__ bias, float* __restrict__ out,
    int K, int N, int kslice)
{
    const int t  = threadIdx.x;
    const int j0 = blockIdx.x << 6;
    const int m0 = blockIdx.y << 7;
    const int z  = blockIdx.z;
    const int kbeg = z * kslice;

    __shared__ __align__(16) float As[16 * 132];
    __shared__ __align__(16) float Bs[16 * 64];

    float acc[8][4];
#pragma unroll
    for (int a = 0; a < 8; ++a)
#pragma unroll
        for (int b = 0; b < 4; ++b) acc[a][b] = 0.f;

    const int a_m  = t >> 2;
    const int a_k  = (t & 3) << 2;
    const int b_j  = t & 63;
    const int b_k0 = (t >> 6) << 2;
    const int ms = (t >> 4) << 3;
    const int js = (t & 15) << 2;

    for (int kb = 0; kb < kslice; kb += 16) {
        int kb0 = kbeg + kb;
#pragma unroll
        for (int r = 0; r < 2; ++r) {
            int m = m0 + a_m + (r << 6);
            float4 av = *(const float4*)(A + (size_t)m * K + kb0 + a_k);
            As[(a_k + 0) * 132 + a_m + (r << 6)] = av.x;
            As[(a_k + 1) * 132 + a_m + (r << 6)] = av.y;
            As[(a_k + 2) * 132 + a_m + (r << 6)] = av.z;
            As[(a_k + 3) * 132 + a_m + (r << 6)] = av.w;
        }
        {
            float4 bv = *(const float4*)(Bw + (size_t)(j0 + b_j) * K + kb0 + b_k0);
            Bs[(b_k0 + 0) * 64 + b_j] = bv.x;
            Bs[(b_k0 + 1) * 64 + b_j] = bv.y;
            Bs[(b_k0 + 2) * 64 + b_j] = bv.z;
            Bs[(b_k0 + 3) * 64 + b_j] = bv.w;
        }
        __syncthreads();
#pragma unroll
        for (int kk = 0; kk < 16; ++kk) {
            float4 A0 = *(const float4*)&As[kk * 132 + ms];
            float4 A1 = *(const float4*)&As[kk * 132 + ms + 4];
            float4 B0 = *(const float4*)&Bs[(kk << 6) + js];
            float av[8] = {A0.x, A0.y, A0.z, A0.w, A1.x, A1.y, A1.z, A1.w};
            float bv[4] = {B0.x, B0.y, B0.z, B0.w};
#pragma unroll
            for (int mm = 0; mm < 8; ++mm)
#pragma unroll
                for (int jj = 0; jj < 4; ++jj)
                    acc[mm][jj] = fmaf(av[mm], bv[jj], acc[mm][jj]);
        }
        __syncthreads();
    }

    if (gridDim.z == 1) {
        float4 b4 = *(const float4*)(bias + j0 + js);
#pragma unroll
        for (int mm = 0; mm < 8; ++mm) {
            float4 o;
            o.x = acc[mm][0] + b4.x;
            o.y = acc[mm][1] + b4.y;
            o.z = acc[mm][2] + b4.z;
            o.w = acc[mm][3] + b4.w;
            if (RELU) {
                o.x = fmaxf(o.x, 0.f); o.y = fmaxf(o.y, 0.f);
                o.z = fmaxf(o.z, 0.f); o.w = fmaxf(o.w, 0.f);
            }
            *(float4*)(out + (size_t)(m0 + ms + mm) * N + j0 + js) = o;
        }
    } else {
        float* po = out + (size_t)z * ((size_t)gridDim.y * 128 * N);
#pragma unroll
        for (int mm = 0; mm < 8; ++mm) {
            float4 o;
            o.x = acc[mm][0]; o.y = acc[mm][1]; o.z = acc[mm][2]; o.w = acc[mm][3];
            *(float4*)(po + (size_t)(m0 + ms + mm) * N + j0 + js) = o;
        }
    }
}

// ---------------- split-K reduce for FC2 (+bias+relu) ----------------------
__global__ __launch_bounds__(256) void fc_reduce_kernel(
    const float* __restrict__ part, const float* __restrict__ bias,
    float* __restrict__ out)
{
    int idx = blockIdx.x * 256 + threadIdx.x;   // < 512*4096
    if (idx >= 512 * 4096) return;
    const size_t MN = (size_t)512 * 4096;
    float s = 0.f;
#pragma unroll
    for (int zz = 0; zz < 8; ++zz) s += part[zz * MN + idx];
    s += bias[idx & 4095];
    out[idx] = fmaxf(s, 0.f);
}

// ---------------- squash of primary caps -----------------------------------
__global__ __launch_bounds__(256) void squash_kernel(
    const float* __restrict__ p, float* __restrict__ u)
{
    int cap = blockIdx.x * 256 + threadIdx.x;   // < 512*512
    if (cap >= 512 * 512) return;
    const float4* pi = (const float4*)(p + (size_t)cap * 8);
    float4 a = pi[0], b = pi[1];
    float sq = a.x * a.x + a.y * a.y + a.z * a.z + a.w * a.w
             + b.x * b.x + b.y * b.y + b.z * b.z + b.w * b.w;
    float f  = sq / (1.f + sq);
    float rs = sqrtf(sq + 1e-8f);
    float4 o0, o1;
    o0.x = (f * a.x) / rs; o0.y = (f * a.y) / rs;
    o0.z = (f * a.z) / rs; o0.w = (f * a.w) / rs;
    o1.x = (f * b.x) / rs; o1.y = (f * b.y) / rs;
    o1.z = (f * b.z) / rs; o1.w = (f * b.w) / rs;
    float4* po = (float4*)(u + (size_t)cap * 8);
    po[0] = o0; po[1] = o1;
}

// ---------------- fused dynamic routing (3 iters), one block per sample ----
// u: [512 samples][512 caps][8]; Wr: [10][512][16][8]; vout: [512][160]
__global__ __launch_bounds__(256) void routing_kernel(
    const float* __restrict__ u, const float* __restrict__ Wr,
    float* __restrict__ vout)
{
    const int b = blockIdx.x;
    const int t = threadIdx.x;
    const int lane = t & 63, wv = t >> 6;

    __shared__ float b_s[10 * 512];
    __shared__ float c_s[10 * 512];
    __shared__ float v_s[160];
    __shared__ float red[4 * 16];

    // each thread only ever touches caps i = t and i = t+256 -> keep u in regs
    const float4* ub = (const float4*)(u + (size_t)b * 4096);
    float4 uA0 = ub[t * 2], uA1 = ub[t * 2 + 1];
    float4 uB0 = ub[(t + 256) * 2], uB1 = ub[(t + 256) * 2 + 1];

    for (int idx = t; idx < 5120; idx += 256) b_s[idx] = 0.f;
    __syncthreads();

    for (int it = 0; it < 3; ++it) {
        // softmax over o (axis=1) for each cap i
        for (int i = t; i < 512; i += 256) {
            float mx = -3.4e38f;
#pragma unroll
            for (int o = 0; o < 10; ++o) mx = fmaxf(mx, b_s[o * 512 + i]);
            float e[10]; float sum = 0.f;
#pragma unroll
            for (int o = 0; o < 10; ++o) { e[o] = expf(b_s[o * 512 + i] - mx); sum += e[o]; }
            float inv = 1.f / sum;
#pragma unroll
            for (int o = 0; o < 10; ++o) c_s[o * 512 + i] = e[o] * inv;
        }
        __syncthreads();

        for (int o = 0; o < 10; ++o) {
            float s[16];
#pragma unroll
            for (int vv = 0; vv < 16; ++vv) s[vv] = 0.f;
            // i = t
            {
                const float4* wr = (const float4*)(Wr + (((size_t)(o << 9) + t) << 7));
                float ci = c_s[(o << 9) + t];
#pragma unroll
                for (int vv = 0; vv < 16; ++vv) {
                    float4 w0 = wr[vv * 2], w1 = wr[vv * 2 + 1];
                    float xh = w0.x * uA0.x + w0.y * uA0.y + w0.z * uA0.z + w0.w * uA0.w
                             + w1.x * uA1.x + w1.y * uA1.y + w1.z * uA1.z + w1.w * uA1.w;
                    s[vv] = fmaf(ci, xh, s[vv]);
                }
            }
            // i = t + 256
            {
                const float4* wr = (const float4*)(Wr + (((size_t)(o << 9) + t + 256) << 7));
                float ci = c_s[(o << 9) + t + 256];
#pragma unroll
                for (int vv = 0; vv < 16; ++vv) {
                    float4 w0 = wr[vv * 2], w1 = wr[vv * 2 + 1];
                    float xh = w0.x * uB0.x + w0.y * uB0.y + w0.z * uB0.z + w0.w * uB0.w
                             + w1.x * uB1.x + w1.y * uB1.y + w1.z * uB1.z + w1.w * uB1.w;
                    s[vv] = fmaf(ci, xh, s[vv]);
                }
            }
            // reduce across 256 threads
#pragma unroll
            for (int vv = 0; vv < 16; ++vv) {
                float x = s[vv];
                for (int off = 32; off > 0; off >>= 1) x += __shfl_xor(x, off);
                s[vv] = x;
            }
            if (lane == 0) {
#pragma unroll
                for (int vv = 0; vv < 16; ++vv) red[(wv << 4) + vv] = s[vv];
            }
            __syncthreads();
            if (t == 0) {
                float tv[16]; float sq = 0.f;
#pragma unroll
                for (int vv = 0; vv < 16; ++vv) {
                    float x = red[vv] + red[16 + vv] + red[32 + vv] + red[48 + vv];
                    tv[vv] = x; sq += x * x;
                }
                float f  = sq / (1.f + sq);
                float rs = sqrtf(sq + 1e-8f);
#pragma unroll
                for (int vv = 0; vv < 16; ++vv) v_s[(o << 4) + vv] = (f * tv[vv]) / rs;
            }
            __syncthreads();
        }

        if (it < 2) {
            // b[o,i] += v[o,:] . x_hat[o,i,:]
            for (int idx = t; idx < 5120; idx += 256) {
                int o = idx >> 9;
                int i = idx & 511;
                bool hi = (idx >> 8) & 1;
                float4 u0 = hi ? uB0 : uA0;
                float4 u1 = hi ? uB1 : uA1;
                const float4* wr = (const float4*)(Wr + (((size_t)(o << 9) + i) << 7));
                float dot = 0.f;
#pragma unroll
                for (int vv = 0; vv < 16; ++vv) {
                    float4 w0 = wr[vv * 2], w1 = wr[vv * 2 + 1];
                    float xh = w0.x * u0.x + w0.y * u0.y + w0.z * u0.z + w0.w * u0.w
                             + w1.x * u1.x + w1.y * u1.y + w1.z * u1.z + w1.w * u1.w;
                    dot = fmaf(v_s[(o << 4) + vv], xh, dot);
                }
                b_s[idx] += dot;
            }
            __syncthreads();
        }
    }

    for (int idx = t; idx < 160; idx += 256) vout[(size_t)b * 160 + idx] = v_s[idx];
}

// ---------------- FC3: [512,4096] x [10,4096]^T + b -> [512,10] ------------
__global__ __launch_bounds__(256) void fc3_kernel(
    const float* __restrict__ f, const float* __restrict__ w,
    const float* __restrict__ bias, float* __restrict__ out)
{
    const int n = blockIdx.x;
    const int t = threadIdx.x;
    const int lane = t & 63, wv = t >> 6;
    const float* fr = f + (size_t)n * 4096;
    float p[10];
#pragma unroll
    for (int j = 0; j < 10; ++j) p[j] = 0.f;
    for (int k = t; k < 4096; k += 256) {
        float x = fr[k];
#pragma unroll
        for (int j = 0; j < 10; ++j) p[j] = fmaf(x, w[j * 4096 + k], p[j]);
    }
    __shared__ float red[4 * 10];
#pragma unroll
    for (int j = 0; j < 10; ++j) {
        float x = p[j];
        for (int off = 32; off > 0; off >>= 1) x += __shfl_xor(x, off);
        p[j] = x;
    }
    if (lane == 0) {
#pragma unroll
        for (int j = 0; j < 10; ++j) red[wv * 10 + j] = p[j];
    }
    __syncthreads();
    if (t < 10)
        out[(size_t)n * 10 + t] = red[t] + red[10 + t] + red[20 + t] + red[30 + t] + bias[t];
}

// ===========================================================================
extern "C" void kernel_launch(void* const* d_in, const int* in_sizes, int n_in,
                              void* d_out, int out_size, void* d_ws, size_t ws_size,
                              hipStream_t stream)
{
    const float* x   = (const float*)d_in[0];
    const float* w1  = (const float*)d_in[1];
    const float* b1  = (const float*)d_in[2];
    const float* w2  = (const float*)d_in[3];
    const float* b2  = (const float*)d_in[4];
    const float* w3  = (const float*)d_in[5];
    const float* b3  = (const float*)d_in[6];
    const float* w4  = (const float*)d_in[7];
    const float* b4  = (const float*)d_in[8];
    const float* w5  = (const float*)d_in[9];
    const float* b5  = (const float*)d_in[10];
    const float* wp  = (const float*)d_in[11];
    const float* bp  = (const float*)d_in[12];
    const float* Wr  = (const float*)d_in[13];
    const float* fw1 = (const float*)d_in[14];
    const float* fb1 = (const float*)d_in[15];
    const float* fw2 = (const float*)d_in[16];
    const float* fb2 = (const float*)d_in[17];
    const float* fw3 = (const float*)d_in[18];
    const float* fb3 = (const float*)d_in[19];
    float* outp = (float*)d_out;

    char* w = (char*)d_ws;
    const size_t R0 = 0;
    const size_t R1 = 38535168;     // 512*96*196*4, 256B-aligned
    float* p1   = (float*)(w + R0);
    float* a2   = (float*)(w + R1);
    float* p2   = (float*)(w + R0);
    float* a3   = (float*)(w + R1);
    float* a4   = (float*)(w + R0);
    float* a5   = (float*)(w + R1);
    float* p3   = (float*)(w + R0);
    float* pc   = (float*)(w + R1);
    float* u    = (float*)(w + R0);
    float* vcap = (float*)(w + R1);
    float* f1   = (float*)(w + R0);
    float* part = (float*)(w + R1 + 16777216);
    float* f2   = (float*)(w + R1);

    // conv1 + relu + pool1 : x -> p1 [512,96,14,14]
    conv1_pool_kernel<<<dim3(37632), dim3(256), 0, stream>>>(x, w1, b1, p1);
    // conv2 + relu : p1 -> a2 [512,256,14,14]
    conv_gemm<96, 14, 14, 3, 1, 256, true><<<dim3(1568, 2), dim3(256), 0, stream>>>(p1, w2, b2, a2);
    // pool2 : a2 -> p2 [512,256,7,7]
    maxpool_kernel<256, 14, 14, 7, 7, 3, 2, 1><<<dim3(25088), dim3(256), 0, stream>>>(a2, p2);
    // conv3 + relu : p2 -> a3 [512,384,7,7]
    conv_gemm<256, 7, 7, 3, 1, 384, true><<<dim3(392, 3), dim3(256), 0, stream>>>(p2, w3, b3, a3);
    // conv4 + relu : a3 -> a4 [512,384,7,7]
    conv_gemm<384, 7, 7, 3, 1, 384, true><<<dim3(392, 3), dim3(256), 0, stream>>>(a3, w4, b4, a4);
    // conv5 + relu : a4 -> a5 [512,256,7,7]
    conv_gemm<384, 7, 7, 3, 1, 256, true><<<dim3(392, 2), dim3(256), 0, stream>>>(a4, w5, b5, a5);
    // pool3 : a5 -> p3 [512,256,5,5]
    maxpool_kernel<256, 7, 7, 5, 5, 3, 1, 0><<<dim3(12800), dim3(256), 0, stream>>>(a5, p3);
    // primary caps conv (k2,s1,p0, no relu) : p3 -> pc [512,256,4,4]
    conv_gemm<256, 5, 5, 2, 0, 256, false><<<dim3(128, 2), dim3(256), 0, stream>>>(p3, wp, bp, pc);
    // squash : pc -> u [512,512,8]
    squash_kernel<<<dim3(1024), dim3(256), 0, stream>>>(pc, u);
    // dynamic routing : u, Wr -> vcap [512,160]
    routing_kernel<<<dim3(512), dim3(256), 0, stream>>>(u, Wr, vcap);
    // FC1 + relu : vcap -> f1 [512,4096]
    fc_gemm<true><<<dim3(64, 4, 1), dim3(256), 0, stream>>>(vcap, fw1, fb1, f1, 160, 4096, 160);
    // FC2 split-K=8 partials : f1 -> part [8,512,4096]
    fc_gemm<false><<<dim3(64, 4, 8), dim3(256), 0, stream>>>(f1, fw2, (const float*)nullptr, part, 4096, 4096, 512);
    // reduce + bias + relu : part -> f2 [512,4096]
    fc_reduce_kernel<<<dim3(8192), dim3(256), 0, stream>>>(part, fb2, f2);
    // FC3 : f2 -> out [512,10]
    fc3_kernel<<<dim3(512), dim3(256), 0, stream>>>(f2, fw3, fb3, outp);
}

// Round 2
// 2935.136 us; speedup vs baseline: 1.6510x; 1.6510x over previous
//
#include <hip/hip_runtime.h>
#include <math.h>

// ===========================================================================
// AlexCapsNet forward. Big convs + FC2 via fp16x3-split MFMA (16x16x32_f16).
// a = ah + al/2048 (al stored pre-scaled by 2048 to stay in f16 normal range).
// C = sum ah*bh  +  (sum ah*bl + al*bh) / 2048      (al*bl dropped, ~2^-22)
// ws peak usage ~130 MB (proven >=141 MB available in round 1).
// ===========================================================================

#define BATCH 512

typedef _Float16 half8 __attribute__((ext_vector_type(8)));
typedef float   float4v __attribute__((ext_vector_type(4)));

// ---------------- fp32 -> (hi f16, lo f16*2048) split ----------------------
__global__ __launch_bounds__(256) void split_kernel(
    const float* __restrict__ src, _Float16* __restrict__ hi,
    _Float16* __restrict__ lo, int n)
{
    int idx = blockIdx.x * 256 + threadIdx.x;
    if (idx >= n) return;
    float v = src[idx];
    _Float16 h = (_Float16)v;
    hi[idx] = h;
    lo[idx] = (_Float16)((v - (float)h) * 2048.0f);
}

// ---------------- conv1(1->96,3x3,p1) + relu + maxpool(3,2,1) fused --------
__global__ __launch_bounds__(256) void conv1_pool_kernel(
    const float* __restrict__ x, const float* __restrict__ w1,
    const float* __restrict__ b1, float* __restrict__ out)
{
    int idx = blockIdx.x * 256 + threadIdx.x;       // total = 512*96*14*14
    if (idx >= 512 * 96 * 14 * 14) return;
    int ow = idx % 14; int t1 = idx / 14;
    int oh = t1 % 14;  int t2 = t1 / 14;
    int oc = t2 % 96;  int n  = t2 / 96;
    const float* xi = x + n * 784;
    float w[9];
#pragma unroll
    for (int i = 0; i < 9; ++i) w[i] = w1[oc * 9 + i];
    float bias = b1[oc];
    float best = -3.4e38f;
#pragma unroll
    for (int dy = 0; dy < 3; ++dy) {
        int ph = oh * 2 - 1 + dy;
        if ((unsigned)ph >= 28u) continue;
#pragma unroll
        for (int dx = 0; dx < 3; ++dx) {
            int pw = ow * 2 - 1 + dx;
            if ((unsigned)pw >= 28u) continue;
            float s = bias;
#pragma unroll
            for (int ky = 0; ky < 3; ++ky) {
                int iy = ph - 1 + ky;
                if ((unsigned)iy >= 28u) continue;
#pragma unroll
                for (int kx = 0; kx < 3; ++kx) {
                    int ix = pw - 1 + kx;
                    if ((unsigned)ix >= 28u) continue;
                    s = fmaf(w[ky * 3 + kx], xi[iy * 28 + ix], s);
                }
            }
            s = fmaxf(s, 0.f);
            best = fmaxf(best, s);
        }
    }
    out[idx] = best;
}

// ---------------- generic maxpool (NB = batch count processed) -------------
template<int NB, int C, int H, int W, int OH, int OW, int KS, int STR, int PADP>
__global__ __launch_bounds__(256) void maxpool_kernel(
    const float* __restrict__ in, float* __restrict__ out)
{
    constexpr int TOTAL = NB * C * OH * OW;
    int idx = blockIdx.x * 256 + threadIdx.x;
    if (idx >= TOTAL) return;
    int ow = idx % OW; int t1 = idx / OW;
    int oh = t1 % OH;  int t2 = t1 / OH;
    int c  = t2 % C;   int n  = t2 / C;
    const float* ip = in + (size_t)(n * C + c) * (H * W);
    float best = -3.4e38f;
#pragma unroll
    for (int dy = 0; dy < KS; ++dy) {
        int ih = oh * STR - PADP + dy;
        if ((unsigned)ih >= (unsigned)H) continue;
#pragma unroll
        for (int dx = 0; dx < KS; ++dx) {
            int iw = ow * STR - PADP + dx;
            if ((unsigned)iw >= (unsigned)W) continue;
            best = fmaxf(best, ip[ih * W + iw]);
        }
    }
    out[idx] = best;
}

// ---------------- fp16x3 MFMA implicit-GEMM conv ---------------------------
// M = OC (tile 128), N = batch*OHW (tile 128), K = IC*KH*KH (step 32).
// Weights pre-split (whi/wlo f16 [OC][K]); activations fp32, split on the fly.
// 4 waves, each computes 64x64 via 4x4 tiles of 16x16x32_f16 MFMA.
template<int IC, int H, int W, int KH, int PAD, int OC, bool RELU>
__global__ __launch_bounds__(256, 2) void conv_f16x3(
    const float* __restrict__ in, const _Float16* __restrict__ whi,
    const _Float16* __restrict__ wlo, const float* __restrict__ bias,
    float* __restrict__ out, int n_base)
{
    constexpr int OH  = H + 2 * PAD - KH + 1;
    constexpr int OW  = W + 2 * PAD - KH + 1;
    constexpr int OHW = OH * OW;
    constexpr int K   = IC * KH * KH;
    constexpr int KK  = KH * KH;
    constexpr int RS  = 40;   // f16 row stride (32 data + 8 pad)
    static_assert(K % 32 == 0, "K step");

    const int t    = threadIdx.x;
    const int lane = t & 63;
    const int wid  = t >> 6;
    const int wm   = (wid >> 1) << 6;
    const int wn   = (wid & 1) << 6;
    const int l15  = lane & 15;
    const int quad = lane >> 4;

    __shared__ __align__(16) _Float16 Ah[128 * RS];
    __shared__ __align__(16) _Float16 Al[128 * RS];
    __shared__ __align__(16) _Float16 Bh[128 * RS];
    __shared__ __align__(16) _Float16 Bl[128 * RS];

    const int n0 = blockIdx.x << 7;
    const int m0 = blockIdx.y << 7;

    float4v acc1[16], acc2[16];
#pragma unroll
    for (int i = 0; i < 16; ++i) {
        acc1[i] = (float4v)(0.f);
        acc2[i] = (float4v)(0.f);
    }

    // A staging: thread -> row am, 16 f16 at ak
    const int am = t >> 1;
    const int ak = (t & 1) << 4;
    const _Float16* wh_p = whi + (size_t)(m0 + am) * K + ak;
    const _Float16* wl_p = wlo + (size_t)(m0 + am) * K + ak;

    // B staging: thread -> column n_u, two 8-k units (k8a and k8a+16)
    const int n_u  = t & 127;
    const int gn_u = n_base + n0 + n_u;
    const int b_u  = gn_u / OHW;
    const int p_u  = gn_u - b_u * OHW;
    const int oh_u = p_u / OW;
    const int ow_u = p_u - oh_u * OW;
    const float* inb = in + (size_t)b_u * (IC * H * W);
    const int k8a = (t >> 7) << 3;   // 0 or 8

    for (int kb = 0; kb < K; kb += 32) {
        // ---- stage A (pre-split weights) ----
        *(half8*)&Ah[am * RS + ak]     = *(const half8*)(wh_p + kb);
        *(half8*)&Ah[am * RS + ak + 8] = *(const half8*)(wh_p + kb + 8);
        *(half8*)&Al[am * RS + ak]     = *(const half8*)(wl_p + kb);
        *(half8*)&Al[am * RS + ak + 8] = *(const half8*)(wl_p + kb + 8);
        // ---- stage B (im2col gather fp32 -> split) ----
#pragma unroll
        for (int uu = 0; uu < 2; ++uu) {
            int k0 = kb + k8a + uu * 16;
            half8 hv, lv;
#pragma unroll
            for (int j = 0; j < 8; ++j) {
                int k  = k0 + j;
                int ic = k / KK;
                int rr = k - ic * KK;
                int kh = rr / KH;
                int kw = rr - kh * KH;
                int ih = oh_u + kh - PAD;
                int iw = ow_u + kw - PAD;
                float v = 0.f;
                if ((unsigned)ih < (unsigned)H && (unsigned)iw < (unsigned)W)
                    v = inb[ic * (H * W) + ih * W + iw];
                _Float16 h = (_Float16)v;
                hv[j] = h;
                lv[j] = (_Float16)((v - (float)h) * 2048.0f);
            }
            *(half8*)&Bh[n_u * RS + k8a + uu * 16] = hv;
            *(half8*)&Bl[n_u * RS + k8a + uu * 16] = lv;
        }
        __syncthreads();
        // ---- compute ----
        half8 ah[4], al[4], bh[4], bl[4];
#pragma unroll
        for (int i = 0; i < 4; ++i) {
            int ar = wm + i * 16 + l15;
            int br = wn + i * 16 + l15;
            ah[i] = *(const half8*)&Ah[ar * RS + quad * 8];
            al[i] = *(const half8*)&Al[ar * RS + quad * 8];
            bh[i] = *(const half8*)&Bh[br * RS + quad * 8];
            bl[i] = *(const half8*)&Bl[br * RS + quad * 8];
        }
#pragma unroll
        for (int mi = 0; mi < 4; ++mi)
#pragma unroll
            for (int ni = 0; ni < 4; ++ni) {
                int ix = mi * 4 + ni;
                acc1[ix] = __builtin_amdgcn_mfma_f32_16x16x32_f16(ah[mi], bh[ni], acc1[ix], 0, 0, 0);
                acc2[ix] = __builtin_amdgcn_mfma_f32_16x16x32_f16(ah[mi], bl[ni], acc2[ix], 0, 0, 0);
                acc2[ix] = __builtin_amdgcn_mfma_f32_16x16x32_f16(al[mi], bh[ni], acc2[ix], 0, 0, 0);
            }
        __syncthreads();
    }
    // ---- epilogue: combine, bias(+relu), scatter NCHW ----
#pragma unroll
    for (int mi = 0; mi < 4; ++mi)
#pragma unroll
        for (int ni = 0; ni < 4; ++ni) {
            int ix = mi * 4 + ni;
            int gn = n_base + n0 + wn + ni * 16 + l15;
            int b  = gn / OHW;
            int p  = gn - b * OHW;
#pragma unroll
            for (int r = 0; r < 4; ++r) {
                int m = m0 + wm + mi * 16 + quad * 4 + r;
                float v = acc1[ix][r] + acc2[ix][r] * (1.0f / 2048.0f) + bias[m];
                if (RELU) v = fmaxf(v, 0.f);
                out[((size_t)b * OC + m) * OHW + p] = v;
            }
        }
}

// ---------------- fp16x3 MFMA FC2: [512,4096] x [4096,4096]^T, split-K -----
// A pre-split (f1h/f1l), B = fw2 fp32 [N][K], split on the fly. Partials out.
__global__ __launch_bounds__(256, 2) void fc2_f16x3(
    const _Float16* __restrict__ f1h, const _Float16* __restrict__ f1l,
    const float* __restrict__ Bw, float* __restrict__ part, int kslice)
{
    constexpr int K = 4096, N = 4096;
    constexpr int RS = 40;
    const int t    = threadIdx.x;
    const int lane = t & 63;
    const int wid  = t >> 6;
    const int wm   = (wid >> 1) << 6;
    const int wn   = (wid & 1) << 6;
    const int l15  = lane & 15;
    const int quad = lane >> 4;

    __shared__ __align__(16) _Float16 Ah[128 * RS];
    __shared__ __align__(16) _Float16 Al[128 * RS];
    __shared__ __align__(16) _Float16 Bh[128 * RS];
    __shared__ __align__(16) _Float16 Bl[128 * RS];

    const int n0 = blockIdx.x << 7;
    const int m0 = blockIdx.y << 7;
    const int kbeg = blockIdx.z * kslice;

    float4v acc1[16], acc2[16];
#pragma unroll
    for (int i = 0; i < 16; ++i) {
        acc1[i] = (float4v)(0.f);
        acc2[i] = (float4v)(0.f);
    }

    const int am = t >> 1;
    const int ak = (t & 1) << 4;
    const _Float16* ah_p = f1h + (size_t)(m0 + am) * K + kbeg + ak;
    const _Float16* al_p = f1l + (size_t)(m0 + am) * K + kbeg + ak;
    const float*    bw_p = Bw  + (size_t)(n0 + am) * K + kbeg + ak;

    for (int kb = 0; kb < kslice; kb += 32) {
        *(half8*)&Ah[am * RS + ak]     = *(const half8*)(ah_p + kb);
        *(half8*)&Ah[am * RS + ak + 8] = *(const half8*)(ah_p + kb + 8);
        *(half8*)&Al[am * RS + ak]     = *(const half8*)(al_p + kb);
        *(half8*)&Al[am * RS + ak + 8] = *(const half8*)(al_p + kb + 8);
        {
            half8 hv0, lv0, hv1, lv1;
#pragma unroll
            for (int j = 0; j < 8; ++j) {
                float v = bw_p[kb + j];
                _Float16 h = (_Float16)v;
                hv0[j] = h;
                lv0[j] = (_Float16)((v - (float)h) * 2048.0f);
            }
#pragma unroll
            for (int j = 0; j < 8; ++j) {
                float v = bw_p[kb + 8 + j];
                _Float16 h = (_Float16)v;
                hv1[j] = h;
                lv1[j] = (_Float16)((v - (float)h) * 2048.0f);
            }
            *(half8*)&Bh[am * RS + ak]     = hv0;
            *(half8*)&Bh[am * RS + ak + 8] = hv1;
            *(half8*)&Bl[am * RS + ak]     = lv0;
            *(half8*)&Bl[am * RS + ak + 8] = lv1;
        }
        __syncthreads();
        half8 ah[4], al[4], bh[4], bl[4];
#pragma unroll
        for (int i = 0; i < 4; ++i) {
            int ar = wm + i * 16 + l15;
            int br = wn + i * 16 + l15;
            ah[i] = *(const half8*)&Ah[ar * RS + quad * 8];
            al[i] = *(const half8*)&Al[ar * RS + quad * 8];
            bh[i] = *(const half8*)&Bh[br * RS + quad * 8];
            bl[i] = *(const half8*)&Bl[br * RS + quad * 8];
        }
#pragma unroll
        for (int mi = 0; mi < 4; ++mi)
#pragma unroll
            for (int ni = 0; ni < 4; ++ni) {
                int ix = mi * 4 + ni;
                acc1[ix] = __builtin_amdgcn_mfma_f32_16x16x32_f16(ah[mi], bh[ni], acc1[ix], 0, 0, 0);
                acc2[ix] = __builtin_amdgcn_mfma_f32_16x16x32_f16(ah[mi], bl[ni], acc2[ix], 0, 0, 0);
                acc2[ix] = __builtin_amdgcn_mfma_f32_16x16x32_f16(al[mi], bh[ni], acc2[ix], 0, 0, 0);
            }
        __syncthreads();
    }
    float* po = part + (size_t)blockIdx.z * (512 * 4096);
#pragma unroll
    for (int mi = 0; mi < 4; ++mi)
#pragma unroll
        for (int ni = 0; ni < 4; ++ni) {
            int ix = mi * 4 + ni;
            int gn = n0 + wn + ni * 16 + l15;
#pragma unroll
            for (int r = 0; r < 4; ++r) {
                int m = m0 + wm + mi * 16 + quad * 4 + r;
                po[(size_t)m * N + gn] = acc1[ix][r] + acc2[ix][r] * (1.0f / 2048.0f);
            }
        }
}

// ---------------- split-K reduce for FC2 (+bias+relu) ----------------------
__global__ __launch_bounds__(256) void fc2_reduce_kernel(
    const float* __restrict__ part, const float* __restrict__ bias,
    float* __restrict__ out)
{
    int idx = blockIdx.x * 256 + threadIdx.x;   // < 512*4096
    if (idx >= 512 * 4096) return;
    const size_t MN = (size_t)512 * 4096;
    float s = 0.f;
#pragma unroll
    for (int zz = 0; zz < 4; ++zz) s += part[zz * MN + idx];
    s += bias[idx & 4095];
    out[idx] = fmaxf(s, 0.f);
}

// ---------------- FC1 fp32 GEMM (K=160, small) -----------------------------
template<bool RELU>
__global__ __launch_bounds__(256) void fc_gemm(
    const float* __restrict__ A, const float* __restrict__ Bw,
    const float* __restrict__ bias, float* __restrict__ out,
    int K, int N)
{
    const int t  = threadIdx.x;
    const int j0 = blockIdx.x << 6;
    const int m0 = blockIdx.y << 7;

    __shared__ __align__(16) float As[16 * 132];
    __shared__ __align__(16) float Bs[16 * 64];

    float acc[8][4];
#pragma unroll
    for (int a = 0; a < 8; ++a)
#pragma unroll
        for (int b = 0; b < 4; ++b) acc[a][b] = 0.f;

    const int a_m  = t >> 2;
    const int a_k  = (t & 3) << 2;
    const int b_j  = t & 63;
    const int b_k0 = (t >> 6) << 2;
    const int ms = (t >> 4) << 3;
    const int js = (t & 15) << 2;

    for (int kb0 = 0; kb0 < K; kb0 += 16) {
#pragma unroll
        for (int r = 0; r < 2; ++r) {
            int m = m0 + a_m + (r << 6);
            float4 av = *(const float4*)(A + (size_t)m * K + kb0 + a_k);
            As[(a_k + 0) * 132 + a_m + (r << 6)] = av.x;
            As[(a_k + 1) * 132 + a_m + (r << 6)] = av.y;
            As[(a_k + 2) * 132 + a_m + (r << 6)] = av.z;
            As[(a_k + 3) * 132 + a_m + (r << 6)] = av.w;
        }
        {
            float4 bv = *(const float4*)(Bw + (size_t)(j0 + b_j) * K + kb0 + b_k0);
            Bs[(b_k0 + 0) * 64 + b_j] = bv.x;
            Bs[(b_k0 + 1) * 64 + b_j] = bv.y;
            Bs[(b_k0 + 2) * 64 + b_j] = bv.z;
            Bs[(b_k0 + 3) * 64 + b_j] = bv.w;
        }
        __syncthreads();
#pragma unroll
        for (int kk = 0; kk < 16; ++kk) {
            float4 A0 = *(const float4*)&As[kk * 132 + ms];
            float4 A1 = *(const float4*)&As[kk * 132 + ms + 4];
            float4 B0 = *(const float4*)&Bs[(kk << 6) + js];
            float av[8] = {A0.x, A0.y, A0.z, A0.w, A1.x, A1.y, A1.z, A1.w};
            float bv[4] = {B0.x, B0.y, B0.z, B0.w};
#pragma unroll
            for (int mm = 0; mm < 8; ++mm)
#pragma unroll
                for (int jj = 0; jj < 4; ++jj)
                    acc[mm][jj] = fmaf(av[mm], bv[jj], acc[mm][jj]);
        }
        __syncthreads();
    }
    float4 b4 = *(const float4*)(bias + j0 + js);
#pragma unroll
    for (int mm = 0; mm < 8; ++mm) {
        float4 o;
        o.x = acc[mm][0] + b4.x;
        o.y = acc[mm][1] + b4.y;
        o.z = acc[mm][2] + b4.z;
        o.w = acc[mm][3] + b4.w;
        if (RELU) {
            o.x = fmaxf(o.x, 0.f); o.y = fmaxf(o.y, 0.f);
            o.z = fmaxf(o.z, 0.f); o.w = fmaxf(o.w, 0.f);
        }
        *(float4*)(out + (size_t)(m0 + ms + mm) * N + j0 + js) = o;
    }
}

// ---------------- squash of primary caps -----------------------------------
__global__ __launch_bounds__(256) void squash_kernel(
    const float* __restrict__ p, float* __restrict__ u)
{
    int cap = blockIdx.x * 256 + threadIdx.x;   // < 512*512
    if (cap >= 512 * 512) return;
    const float4* pi = (const float4*)(p + (size_t)cap * 8);
    float4 a = pi[0], b = pi[1];
    float sq = a.x * a.x + a.y * a.y + a.z * a.z + a.w * a.w
             + b.x * b.x + b.y * b.y + b.z * b.z + b.w * b.w;
    float f  = sq / (1.f + sq);
    float rs = sqrtf(sq + 1e-8f);
    float4 o0, o1;
    o0.x = (f * a.x) / rs; o0.y = (f * a.y) / rs;
    o0.z = (f * a.z) / rs; o0.w = (f * a.w) / rs;
    o1.x = (f * b.x) / rs; o1.y = (f * b.y) / rs;
    o1.z = (f * b.z) / rs; o1.w = (f * b.w) / rs;
    float4* po = (float4*)(u + (size_t)cap * 8);
    po[0] = o0; po[1] = o1;
}

// ---------------- fused dynamic routing (3 iters), one block per sample ----
__global__ __launch_bounds__(256) void routing_kernel(
    const float* __restrict__ u, const float* __restrict__ Wr,
    float* __restrict__ vout)
{
    const int b = blockIdx.x;
    const int t = threadIdx.x;
    const int lane = t & 63, wv = t >> 6;

    __shared__ float b_s[10 * 512];
    __shared__ float c_s[10 * 512];
    __shared__ float v_s[160];
    __shared__ float red[4 * 16];

    const float4* ub = (const float4*)(u + (size_t)b * 4096);
    float4 uA0 = ub[t * 2], uA1 = ub[t * 2 + 1];
    float4 uB0 = ub[(t + 256) * 2], uB1 = ub[(t + 256) * 2 + 1];

    for (int idx = t; idx < 5120; idx += 256) b_s[idx] = 0.f;
    __syncthreads();

    for (int it = 0; it < 3; ++it) {
        for (int i = t; i < 512; i += 256) {
            float mx = -3.4e38f;
#pragma unroll
            for (int o = 0; o < 10; ++o) mx = fmaxf(mx, b_s[o * 512 + i]);
            float e[10]; float sum = 0.f;
#pragma unroll
            for (int o = 0; o < 10; ++o) { e[o] = expf(b_s[o * 512 + i] - mx); sum += e[o]; }
            float inv = 1.f / sum;
#pragma unroll
            for (int o = 0; o < 10; ++o) c_s[o * 512 + i] = e[o] * inv;
        }
        __syncthreads();

        for (int o = 0; o < 10; ++o) {
            float s[16];
#pragma unroll
            for (int vv = 0; vv < 16; ++vv) s[vv] = 0.f;
            {
                const float4* wr = (const float4*)(Wr + (((size_t)(o << 9) + t) << 7));
                float ci = c_s[(o << 9) + t];
#pragma unroll
                for (int vv = 0; vv < 16; ++vv) {
                    float4 w0 = wr[vv * 2], w1 = wr[vv * 2 + 1];
                    float xh = w0.x * uA0.x + w0.y * uA0.y + w0.z * uA0.z + w0.w * uA0.w
                             + w1.x * uA1.x + w1.y * uA1.y + w1.z * uA1.z + w1.w * uA1.w;
                    s[vv] = fmaf(ci, xh, s[vv]);
                }
            }
            {
                const float4* wr = (const float4*)(Wr + (((size_t)(o << 9) + t + 256) << 7));
                float ci = c_s[(o << 9) + t + 256];
#pragma unroll
                for (int vv = 0; vv < 16; ++vv) {
                    float4 w0 = wr[vv * 2], w1 = wr[vv * 2 + 1];
                    float xh = w0.x * uB0.x + w0.y * uB0.y + w0.z * uB0.z + w0.w * uB0.w
                             + w1.x * uB1.x + w1.y * uB1.y + w1.z * uB1.z + w1.w * uB1.w;
                    s[vv] = fmaf(ci, xh, s[vv]);
                }
            }
#pragma unroll
            for (int vv = 0; vv < 16; ++vv) {
                float x = s[vv];
                for (int off = 32; off > 0; off >>= 1) x += __shfl_xor(x, off);
                s[vv] = x;
            }
            if (lane == 0) {
#pragma unroll
                for (int vv = 0; vv < 16; ++vv) red[(wv << 4) + vv] = s[vv];
            }
            __syncthreads();
            if (t == 0) {
                float tv[16]; float sq = 0.f;
#pragma unroll
                for (int vv = 0; vv < 16; ++vv) {
                    float x = red[vv] + red[16 + vv] + red[32 + vv] + red[48 + vv];
                    tv[vv] = x; sq += x * x;
                }
                float f  = sq / (1.f + sq);
                float rs = sqrtf(sq + 1e-8f);
#pragma unroll
                for (int vv = 0; vv < 16; ++vv) v_s[(o << 4) + vv] = (f * tv[vv]) / rs;
            }
            __syncthreads();
        }

        if (it < 2) {
            for (int idx = t; idx < 5120; idx += 256) {
                int o = idx >> 9;
                int i = idx & 511;
                bool hi = (idx >> 8) & 1;
                float4 u0 = hi ? uB0 : uA0;
                float4 u1 = hi ? uB1 : uA1;
                const float4* wr = (const float4*)(Wr + (((size_t)(o << 9) + i) << 7));
                float dot = 0.f;
#pragma unroll
                for (int vv = 0; vv < 16; ++vv) {
                    float4 w0 = wr[vv * 2], w1 = wr[vv * 2 + 1];
                    float xh = w0.x * u0.x + w0.y * u0.y + w0.z * u0.z + w0.w * u0.w
                             + w1.x * u1.x + w1.y * u1.y + w1.z * u1.z + w1.w * u1.w;
                    dot = fmaf(v_s[(o << 4) + vv], xh, dot);
                }
                b_s[idx] += dot;
            }
            __syncthreads();
        }
    }

    for (int idx = t; idx < 160; idx += 256) vout[(size_t)b * 160 + idx] = v_s[idx];
}

// ---------------- FC3: [512,4096] x [10,4096]^T + b -> [512,10] ------------
__global__ __launch_bounds__(256) void fc3_kernel(
    const float* __restrict__ f, const float* __restrict__ w,
    const float* __restrict__ bias, float* __restrict__ out)
{
    const int n = blockIdx.x;
    const int t = threadIdx.x;
    const int lane = t & 63, wv = t >> 6;
    const float* fr = f + (size_t)n * 4096;
    float p[10];
#pragma unroll
    for (int j = 0; j < 10; ++j) p[j] = 0.f;
    for (int k = t; k < 4096; k += 256) {
        float x = fr[k];
#pragma unroll
        for (int j = 0; j < 10; ++j) p[j] = fmaf(x, w[j * 4096 + k], p[j]);
    }
    __shared__ float red[4 * 10];
#pragma unroll
    for (int j = 0; j < 10; ++j) {
        float x = p[j];
        for (int off = 32; off > 0; off >>= 1) x += __shfl_xor(x, off);
        p[j] = x;
    }
    if (lane == 0) {
#pragma unroll
        for (int j = 0; j < 10; ++j) red[wv * 10 + j] = p[j];
    }
    __syncthreads();
    if (t < 10)
        out[(size_t)n * 10 + t] = red[t] + red[10 + t] + red[20 + t] + red[30 + t] + bias[t];
}

// ===========================================================================
extern "C" void kernel_launch(void* const* d_in, const int* in_sizes, int n_in,
                              void* d_out, int out_size, void* d_ws, size_t ws_size,
                              hipStream_t stream)
{
    const float* x   = (const float*)d_in[0];
    const float* w1  = (const float*)d_in[1];
    const float* b1  = (const float*)d_in[2];
    const float* w2  = (const float*)d_in[3];
    const float* b2  = (const float*)d_in[4];
    const float* w3  = (const float*)d_in[5];
    const float* b3  = (const float*)d_in[6];
    const float* w4  = (const float*)d_in[7];
    const float* b4  = (const float*)d_in[8];
    const float* w5  = (const float*)d_in[9];
    const float* b5  = (const float*)d_in[10];
    const float* wp  = (const float*)d_in[11];
    const float* bp  = (const float*)d_in[12];
    const float* Wr  = (const float*)d_in[13];
    const float* fw1 = (const float*)d_in[14];
    const float* fb1 = (const float*)d_in[15];
    const float* fw2 = (const float*)d_in[16];
    const float* fb2 = (const float*)d_in[17];
    const float* fw3 = (const float*)d_in[18];
    const float* fb3 = (const float*)d_in[19];
    float* outp = (float*)d_out;

    char* w = (char*)d_ws;
    // ---- byte offsets (peak ~130 MB; round-1 proved >=141 MB) ----
    float*    p1   = (float*)(w + 0);              // 38,535,168 B
    float*    a2h  = (float*)(w + 38535168);       // 51,380,224 B (half batch)
    float*    p2   = (float*)(w + 89915392);       // 25,690,112 B
    _Float16* w2h  = (_Float16*)(w + 115605504);
    _Float16* w2l  = (_Float16*)(w + 116047872);
    _Float16* w3h  = (_Float16*)(w + 116490240);
    _Float16* w3l  = (_Float16*)(w + 118259712);
    _Float16* w4h  = (_Float16*)(w + 120029184);
    _Float16* w4l  = (_Float16*)(w + 122683392);
    _Float16* w5h  = (_Float16*)(w + 125337600);
    _Float16* w5l  = (_Float16*)(w + 127107072);
    _Float16* wph  = (_Float16*)(w + 128876544);
    _Float16* wpl  = (_Float16*)(w + 129400832);   // end 129,925,120
    float*    a3   = (float*)(w + 0);
    float*    a4   = (float*)(w + 38535168);
    float*    a5   = (float*)(w + 0);
    float*    p3   = (float*)(w + 25690112);
    float*    pc   = (float*)(w + 38535168);
    float*    u    = (float*)(w + 46923776);
    float*    vcap = (float*)(w + 55312384);
    float*    f1   = (float*)(w + 55640064);
    _Float16* f1h  = (_Float16*)(w + 64028672);
    _Float16* f1l  = (_Float16*)(w + 68222976);
    float*    part = (float*)(w + 72417280);       // 33,554,432 B (4 slices)
    float*    f2   = (float*)(w + 0);

    // ---- pre-split conv weights to f16 hi/lo ----
    split_kernel<<<dim3(864),  dim3(256), 0, stream>>>(w2, w2h, w2l, 221184);
    split_kernel<<<dim3(3456), dim3(256), 0, stream>>>(w3, w3h, w3l, 884736);
    split_kernel<<<dim3(5184), dim3(256), 0, stream>>>(w4, w4h, w4l, 1327104);
    split_kernel<<<dim3(3456), dim3(256), 0, stream>>>(w5, w5h, w5l, 884736);
    split_kernel<<<dim3(1024), dim3(256), 0, stream>>>(wp, wph, wpl, 262144);

    // conv1 + relu + pool1 : x -> p1 [512,96,14,14]
    conv1_pool_kernel<<<dim3(37632), dim3(256), 0, stream>>>(x, w1, b1, p1);

    // conv2 + relu in two batch halves (ws ceiling), each followed by pool2
    // half 0: batches [0,256)
    conv_f16x3<96, 14, 14, 3, 1, 256, true><<<dim3(392, 2), dim3(256), 0, stream>>>(
        p1, w2h, w2l, b2, a2h, 0);
    maxpool_kernel<256, 256, 14, 14, 7, 7, 3, 2, 1><<<dim3(12544), dim3(256), 0, stream>>>(
        a2h, p2);
    // half 1: batches [256,512)
    conv_f16x3<96, 14, 14, 3, 1, 256, true><<<dim3(392, 2), dim3(256), 0, stream>>>(
        p1, w2h, w2l, b2, a2h - (size_t)256 * 256 * 196, 256 * 196);
    maxpool_kernel<256, 256, 14, 14, 7, 7, 3, 2, 1><<<dim3(12544), dim3(256), 0, stream>>>(
        a2h, p2 + (size_t)256 * 256 * 49);

    // conv3 + relu : p2 -> a3 [512,384,7,7]
    conv_f16x3<256, 7, 7, 3, 1, 384, true><<<dim3(196, 3), dim3(256), 0, stream>>>(
        p2, w3h, w3l, b3, a3, 0);
    // conv4 + relu : a3 -> a4 [512,384,7,7]
    conv_f16x3<384, 7, 7, 3, 1, 384, true><<<dim3(196, 3), dim3(256), 0, stream>>>(
        a3, w4h, w4l, b4, a4, 0);
    // conv5 + relu : a4 -> a5 [512,256,7,7]
    conv_f16x3<384, 7, 7, 3, 1, 256, true><<<dim3(196, 2), dim3(256), 0, stream>>>(
        a4, w5h, w5l, b5, a5, 0);
    // pool3 : a5 -> p3 [512,256,5,5]
    maxpool_kernel<512, 256, 7, 7, 5, 5, 3, 1, 0><<<dim3(12800), dim3(256), 0, stream>>>(a5, p3);
    // primary caps conv (k2,s1,p0, no relu) : p3 -> pc [512,256,4,4]
    conv_f16x3<256, 5, 5, 2, 0, 256, false><<<dim3(64, 2), dim3(256), 0, stream>>>(
        p3, wph, wpl, bp, pc, 0);
    // squash : pc -> u [512,512,8]
    squash_kernel<<<dim3(1024), dim3(256), 0, stream>>>(pc, u);
    // dynamic routing : u, Wr -> vcap [512,160]
    routing_kernel<<<dim3(512), dim3(256), 0, stream>>>(u, Wr, vcap);
    // FC1 + relu (fp32, K=160) : vcap -> f1 [512,4096]
    fc_gemm<true><<<dim3(64, 4), dim3(256), 0, stream>>>(vcap, fw1, fb1, f1, 160, 4096);
    // split f1
    split_kernel<<<dim3(8192), dim3(256), 0, stream>>>(f1, f1h, f1l, 2097152);
    // FC2 fp16x3 split-K=4 : f1s, fw2 -> part [4,512,4096]
    fc2_f16x3<<<dim3(32, 4, 4), dim3(256), 0, stream>>>(f1h, f1l, fw2, part, 1024);
    // reduce + bias + relu : part -> f2 [512,4096]
    fc2_reduce_kernel<<<dim3(8192), dim3(256), 0, stream>>>(part, fb2, f2);
    // FC3 : f2 -> out [512,10]
    fc3_kernel<<<dim3(512), dim3(256), 0, stream>>>(f2, fw3, fb3, outp);
}

// Round 3
// 2371.924 us; speedup vs baseline: 2.0430x; 1.2374x over previous
//
#include <hip/hip_runtime.h>
#include <math.h>

// ===========================================================================
// AlexCapsNet forward. Big convs + FC2 via fp16x3-split MFMA (16x16x32_f16).
// a = ah + al/2048 (al stored pre-scaled by 2048 to stay in f16 normal range).
// C = sum ah*bh  +  (sum ah*bl + al*bh) / 2048      (al*bl dropped, ~2^-22)
// Routing: x_hat precomputed to global (half-batch, 84 MB), shuffle-free
// routing kernel. ws peak ~139.5 MB (proven >=141.3 MB in round 1).
// ===========================================================================

#define BATCH 512

typedef _Float16 half8 __attribute__((ext_vector_type(8)));
typedef float   float4v __attribute__((ext_vector_type(4)));

// ---------------- fp32 -> (hi f16, lo f16*2048) split ----------------------
__global__ __launch_bounds__(256) void split_kernel(
    const float* __restrict__ src, _Float16* __restrict__ hi,
    _Float16* __restrict__ lo, int n)
{
    int idx = blockIdx.x * 256 + threadIdx.x;
    if (idx >= n) return;
    float v = src[idx];
    _Float16 h = (_Float16)v;
    hi[idx] = h;
    lo[idx] = (_Float16)((v - (float)h) * 2048.0f);
}

// ---------------- conv1(1->96,3x3,p1) + relu + maxpool(3,2,1) fused --------
__global__ __launch_bounds__(256) void conv1_pool_kernel(
    const float* __restrict__ x, const float* __restrict__ w1,
    const float* __restrict__ b1, float* __restrict__ out)
{
    int idx = blockIdx.x * 256 + threadIdx.x;       // total = 512*96*14*14
    if (idx >= 512 * 96 * 14 * 14) return;
    int ow = idx % 14; int t1 = idx / 14;
    int oh = t1 % 14;  int t2 = t1 / 14;
    int oc = t2 % 96;  int n  = t2 / 96;
    const float* xi = x + n * 784;
    float w[9];
#pragma unroll
    for (int i = 0; i < 9; ++i) w[i] = w1[oc * 9 + i];
    float bias = b1[oc];
    float best = -3.4e38f;
#pragma unroll
    for (int dy = 0; dy < 3; ++dy) {
        int ph = oh * 2 - 1 + dy;
        if ((unsigned)ph >= 28u) continue;
#pragma unroll
        for (int dx = 0; dx < 3; ++dx) {
            int pw = ow * 2 - 1 + dx;
            if ((unsigned)pw >= 28u) continue;
            float s = bias;
#pragma unroll
            for (int ky = 0; ky < 3; ++ky) {
                int iy = ph - 1 + ky;
                if ((unsigned)iy >= 28u) continue;
#pragma unroll
                for (int kx = 0; kx < 3; ++kx) {
                    int ix = pw - 1 + kx;
                    if ((unsigned)ix >= 28u) continue;
                    s = fmaf(w[ky * 3 + kx], xi[iy * 28 + ix], s);
                }
            }
            s = fmaxf(s, 0.f);
            best = fmaxf(best, s);
        }
    }
    out[idx] = best;
}

// ---------------- generic maxpool (NB = batch count processed) -------------
template<int NB, int C, int H, int W, int OH, int OW, int KS, int STR, int PADP>
__global__ __launch_bounds__(256) void maxpool_kernel(
    const float* __restrict__ in, float* __restrict__ out)
{
    constexpr int TOTAL = NB * C * OH * OW;
    int idx = blockIdx.x * 256 + threadIdx.x;
    if (idx >= TOTAL) return;
    int ow = idx % OW; int t1 = idx / OW;
    int oh = t1 % OH;  int t2 = t1 / OH;
    int c  = t2 % C;   int n  = t2 / C;
    const float* ip = in + (size_t)(n * C + c) * (H * W);
    float best = -3.4e38f;
#pragma unroll
    for (int dy = 0; dy < KS; ++dy) {
        int ih = oh * STR - PADP + dy;
        if ((unsigned)ih >= (unsigned)H) continue;
#pragma unroll
        for (int dx = 0; dx < KS; ++dx) {
            int iw = ow * STR - PADP + dx;
            if ((unsigned)iw >= (unsigned)W) continue;
            best = fmaxf(best, ip[ih * W + iw]);
        }
    }
    out[idx] = best;
}

// ---------------- fp16x3 MFMA implicit-GEMM conv ---------------------------
template<int IC, int H, int W, int KH, int PAD, int OC, bool RELU>
__global__ __launch_bounds__(256, 2) void conv_f16x3(
    const float* __restrict__ in, const _Float16* __restrict__ whi,
    const _Float16* __restrict__ wlo, const float* __restrict__ bias,
    float* __restrict__ out, int n_base)
{
    constexpr int OH  = H + 2 * PAD - KH + 1;
    constexpr int OW  = W + 2 * PAD - KH + 1;
    constexpr int OHW = OH * OW;
    constexpr int K   = IC * KH * KH;
    constexpr int KK  = KH * KH;
    constexpr int RS  = 40;   // f16 row stride (32 data + 8 pad)
    static_assert(K % 32 == 0, "K step");

    const int t    = threadIdx.x;
    const int lane = t & 63;
    const int wid  = t >> 6;
    const int wm   = (wid >> 1) << 6;
    const int wn   = (wid & 1) << 6;
    const int l15  = lane & 15;
    const int quad = lane >> 4;

    __shared__ __align__(16) _Float16 Ah[128 * RS];
    __shared__ __align__(16) _Float16 Al[128 * RS];
    __shared__ __align__(16) _Float16 Bh[128 * RS];
    __shared__ __align__(16) _Float16 Bl[128 * RS];

    const int n0 = blockIdx.x << 7;
    const int m0 = blockIdx.y << 7;

    float4v acc1[16], acc2[16];
#pragma unroll
    for (int i = 0; i < 16; ++i) {
        acc1[i] = (float4v)(0.f);
        acc2[i] = (float4v)(0.f);
    }

    const int am = t >> 1;
    const int ak = (t & 1) << 4;
    const _Float16* wh_p = whi + (size_t)(m0 + am) * K + ak;
    const _Float16* wl_p = wlo + (size_t)(m0 + am) * K + ak;

    const int n_u  = t & 127;
    const int gn_u = n_base + n0 + n_u;
    const int b_u  = gn_u / OHW;
    const int p_u  = gn_u - b_u * OHW;
    const int oh_u = p_u / OW;
    const int ow_u = p_u - oh_u * OW;
    const float* inb = in + (size_t)b_u * (IC * H * W);
    const int k8a = (t >> 7) << 3;   // 0 or 8

    for (int kb = 0; kb < K; kb += 32) {
        *(half8*)&Ah[am * RS + ak]     = *(const half8*)(wh_p + kb);
        *(half8*)&Ah[am * RS + ak + 8] = *(const half8*)(wh_p + kb + 8);
        *(half8*)&Al[am * RS + ak]     = *(const half8*)(wl_p + kb);
        *(half8*)&Al[am * RS + ak + 8] = *(const half8*)(wl_p + kb + 8);
#pragma unroll
        for (int uu = 0; uu < 2; ++uu) {
            int k0 = kb + k8a + uu * 16;
            half8 hv, lv;
#pragma unroll
            for (int j = 0; j < 8; ++j) {
                int k  = k0 + j;
                int ic = k / KK;
                int rr = k - ic * KK;
                int kh = rr / KH;
                int kw = rr - kh * KH;
                int ih = oh_u + kh - PAD;
                int iw = ow_u + kw - PAD;
                float v = 0.f;
                if ((unsigned)ih < (unsigned)H && (unsigned)iw < (unsigned)W)
                    v = inb[ic * (H * W) + ih * W + iw];
                _Float16 h = (_Float16)v;
                hv[j] = h;
                lv[j] = (_Float16)((v - (float)h) * 2048.0f);
            }
            *(half8*)&Bh[n_u * RS + k8a + uu * 16] = hv;
            *(half8*)&Bl[n_u * RS + k8a + uu * 16] = lv;
        }
        __syncthreads();
        half8 ah[4], al[4], bh[4], bl[4];
#pragma unroll
        for (int i = 0; i < 4; ++i) {
            int ar = wm + i * 16 + l15;
            int br = wn + i * 16 + l15;
            ah[i] = *(const half8*)&Ah[ar * RS + quad * 8];
            al[i] = *(const half8*)&Al[ar * RS + quad * 8];
            bh[i] = *(const half8*)&Bh[br * RS + quad * 8];
            bl[i] = *(const half8*)&Bl[br * RS + quad * 8];
        }
#pragma unroll
        for (int mi = 0; mi < 4; ++mi)
#pragma unroll
            for (int ni = 0; ni < 4; ++ni) {
                int ix = mi * 4 + ni;
                acc1[ix] = __builtin_amdgcn_mfma_f32_16x16x32_f16(ah[mi], bh[ni], acc1[ix], 0, 0, 0);
                acc2[ix] = __builtin_amdgcn_mfma_f32_16x16x32_f16(ah[mi], bl[ni], acc2[ix], 0, 0, 0);
                acc2[ix] = __builtin_amdgcn_mfma_f32_16x16x32_f16(al[mi], bh[ni], acc2[ix], 0, 0, 0);
            }
        __syncthreads();
    }
#pragma unroll
    for (int mi = 0; mi < 4; ++mi)
#pragma unroll
        for (int ni = 0; ni < 4; ++ni) {
            int ix = mi * 4 + ni;
            int gn = n_base + n0 + wn + ni * 16 + l15;
            int b  = gn / OHW;
            int p  = gn - b * OHW;
#pragma unroll
            for (int r = 0; r < 4; ++r) {
                int m = m0 + wm + mi * 16 + quad * 4 + r;
                float v = acc1[ix][r] + acc2[ix][r] * (1.0f / 2048.0f) + bias[m];
                if (RELU) v = fmaxf(v, 0.f);
                out[((size_t)b * OC + m) * OHW + p] = v;
            }
        }
}

// ---------------- fp16x3 MFMA FC2: [512,4096] x [4096,4096]^T, split-K -----
__global__ __launch_bounds__(256, 2) void fc2_f16x3(
    const _Float16* __restrict__ f1h, const _Float16* __restrict__ f1l,
    const float* __restrict__ Bw, float* __restrict__ part, int kslice)
{
    constexpr int K = 4096, N = 4096;
    constexpr int RS = 40;
    const int t    = threadIdx.x;
    const int lane = t & 63;
    const int wid  = t >> 6;
    const int wm   = (wid >> 1) << 6;
    const int wn   = (wid & 1) << 6;
    const int l15  = lane & 15;
    const int quad = lane >> 4;

    __shared__ __align__(16) _Float16 Ah[128 * RS];
    __shared__ __align__(16) _Float16 Al[128 * RS];
    __shared__ __align__(16) _Float16 Bh[128 * RS];
    __shared__ __align__(16) _Float16 Bl[128 * RS];

    const int n0 = blockIdx.x << 7;
    const int m0 = blockIdx.y << 7;
    const int kbeg = blockIdx.z * kslice;

    float4v acc1[16], acc2[16];
#pragma unroll
    for (int i = 0; i < 16; ++i) {
        acc1[i] = (float4v)(0.f);
        acc2[i] = (float4v)(0.f);
    }

    const int am = t >> 1;
    const int ak = (t & 1) << 4;
    const _Float16* ah_p = f1h + (size_t)(m0 + am) * K + kbeg + ak;
    const _Float16* al_p = f1l + (size_t)(m0 + am) * K + kbeg + ak;
    const float*    bw_p = Bw  + (size_t)(n0 + am) * K + kbeg + ak;

    for (int kb = 0; kb < kslice; kb += 32) {
        *(half8*)&Ah[am * RS + ak]     = *(const half8*)(ah_p + kb);
        *(half8*)&Ah[am * RS + ak + 8] = *(const half8*)(ah_p + kb + 8);
        *(half8*)&Al[am * RS + ak]     = *(const half8*)(al_p + kb);
        *(half8*)&Al[am * RS + ak + 8] = *(const half8*)(al_p + kb + 8);
        {
            half8 hv0, lv0, hv1, lv1;
#pragma unroll
            for (int j = 0; j < 8; ++j) {
                float v = bw_p[kb + j];
                _Float16 h = (_Float16)v;
                hv0[j] = h;
                lv0[j] = (_Float16)((v - (float)h) * 2048.0f);
            }
#pragma unroll
            for (int j = 0; j < 8; ++j) {
                float v = bw_p[kb + 8 + j];
                _Float16 h = (_Float16)v;
                hv1[j] = h;
                lv1[j] = (_Float16)((v - (float)h) * 2048.0f);
            }
            *(half8*)&Bh[am * RS + ak]     = hv0;
            *(half8*)&Bh[am * RS + ak + 8] = hv1;
            *(half8*)&Bl[am * RS + ak]     = lv0;
            *(half8*)&Bl[am * RS + ak + 8] = lv1;
        }
        __syncthreads();
        half8 ah[4], al[4], bh[4], bl[4];
#pragma unroll
        for (int i = 0; i < 4; ++i) {
            int ar = wm + i * 16 + l15;
            int br = wn + i * 16 + l15;
            ah[i] = *(const half8*)&Ah[ar * RS + quad * 8];
            al[i] = *(const half8*)&Al[ar * RS + quad * 8];
            bh[i] = *(const half8*)&Bh[br * RS + quad * 8];
            bl[i] = *(const half8*)&Bl[br * RS + quad * 8];
        }
#pragma unroll
        for (int mi = 0; mi < 4; ++mi)
#pragma unroll
            for (int ni = 0; ni < 4; ++ni) {
                int ix = mi * 4 + ni;
                acc1[ix] = __builtin_amdgcn_mfma_f32_16x16x32_f16(ah[mi], bh[ni], acc1[ix], 0, 0, 0);
                acc2[ix] = __builtin_amdgcn_mfma_f32_16x16x32_f16(ah[mi], bl[ni], acc2[ix], 0, 0, 0);
                acc2[ix] = __builtin_amdgcn_mfma_f32_16x16x32_f16(al[mi], bh[ni], acc2[ix], 0, 0, 0);
            }
        __syncthreads();
    }
    float* po = part + (size_t)blockIdx.z * (512 * 4096);
#pragma unroll
    for (int mi = 0; mi < 4; ++mi)
#pragma unroll
        for (int ni = 0; ni < 4; ++ni) {
            int ix = mi * 4 + ni;
            int gn = n0 + wn + ni * 16 + l15;
#pragma unroll
            for (int r = 0; r < 4; ++r) {
                int m = m0 + wm + mi * 16 + quad * 4 + r;
                po[(size_t)m * N + gn] = acc1[ix][r] + acc2[ix][r] * (1.0f / 2048.0f);
            }
        }
}

// ---------------- split-K reduce for FC2 (+bias+relu) ----------------------
__global__ __launch_bounds__(256) void fc2_reduce_kernel(
    const float* __restrict__ part, const float* __restrict__ bias,
    float* __restrict__ out)
{
    int idx = blockIdx.x * 256 + threadIdx.x;   // < 512*4096
    if (idx >= 512 * 4096) return;
    const size_t MN = (size_t)512 * 4096;
    float s = 0.f;
#pragma unroll
    for (int zz = 0; zz < 4; ++zz) s += part[zz * MN + idx];
    s += bias[idx & 4095];
    out[idx] = fmaxf(s, 0.f);
}

// ---------------- FC1 fp32 GEMM (K=160, small) -----------------------------
template<bool RELU>
__global__ __launch_bounds__(256) void fc_gemm(
    const float* __restrict__ A, const float* __restrict__ Bw,
    const float* __restrict__ bias, float* __restrict__ out,
    int K, int N)
{
    const int t  = threadIdx.x;
    const int j0 = blockIdx.x << 6;
    const int m0 = blockIdx.y << 7;

    __shared__ __align__(16) float As[16 * 132];
    __shared__ __align__(16) float Bs[16 * 64];

    float acc[8][4];
#pragma unroll
    for (int a = 0; a < 8; ++a)
#pragma unroll
        for (int b = 0; b < 4; ++b) acc[a][b] = 0.f;

    const int a_m  = t >> 2;
    const int a_k  = (t & 3) << 2;
    const int b_j  = t & 63;
    const int b_k0 = (t >> 6) << 2;
    const int ms = (t >> 4) << 3;
    const int js = (t & 15) << 2;

    for (int kb0 = 0; kb0 < K; kb0 += 16) {
#pragma unroll
        for (int r = 0; r < 2; ++r) {
            int m = m0 + a_m + (r << 6);
            float4 av = *(const float4*)(A + (size_t)m * K + kb0 + a_k);
            As[(a_k + 0) * 132 + a_m + (r << 6)] = av.x;
            As[(a_k + 1) * 132 + a_m + (r << 6)] = av.y;
            As[(a_k + 2) * 132 + a_m + (r << 6)] = av.z;
            As[(a_k + 3) * 132 + a_m + (r << 6)] = av.w;
        }
        {
            float4 bv = *(const float4*)(Bw + (size_t)(j0 + b_j) * K + kb0 + b_k0);
            Bs[(b_k0 + 0) * 64 + b_j] = bv.x;
            Bs[(b_k0 + 1) * 64 + b_j] = bv.y;
            Bs[(b_k0 + 2) * 64 + b_j] = bv.z;
            Bs[(b_k0 + 3) * 64 + b_j] = bv.w;
        }
        __syncthreads();
#pragma unroll
        for (int kk = 0; kk < 16; ++kk) {
            float4 A0 = *(const float4*)&As[kk * 132 + ms];
            float4 A1 = *(const float4*)&As[kk * 132 + ms + 4];
            float4 B0 = *(const float4*)&Bs[(kk << 6) + js];
            float av[8] = {A0.x, A0.y, A0.z, A0.w, A1.x, A1.y, A1.z, A1.w};
            float bv[4] = {B0.x, B0.y, B0.z, B0.w};
#pragma unroll
            for (int mm = 0; mm < 8; ++mm)
#pragma unroll
                for (int jj = 0; jj < 4; ++jj)
                    acc[mm][jj] = fmaf(av[mm], bv[jj], acc[mm][jj]);
        }
        __syncthreads();
    }
    float4 b4 = *(const float4*)(bias + j0 + js);
#pragma unroll
    for (int mm = 0; mm < 8; ++mm) {
        float4 o;
        o.x = acc[mm][0] + b4.x;
        o.y = acc[mm][1] + b4.y;
        o.z = acc[mm][2] + b4.z;
        o.w = acc[mm][3] + b4.w;
        if (RELU) {
            o.x = fmaxf(o.x, 0.f); o.y = fmaxf(o.y, 0.f);
            o.z = fmaxf(o.z, 0.f); o.w = fmaxf(o.w, 0.f);
        }
        *(float4*)(out + (size_t)(m0 + ms + mm) * N + j0 + js) = o;
    }
}

// ---------------- squash of primary caps -----------------------------------
__global__ __launch_bounds__(256) void squash_kernel(
    const float* __restrict__ p, float* __restrict__ u)
{
    int cap = blockIdx.x * 256 + threadIdx.x;   // < 512*512
    if (cap >= 512 * 512) return;
    const float4* pi = (const float4*)(p + (size_t)cap * 8);
    float4 a = pi[0], b = pi[1];
    float sq = a.x * a.x + a.y * a.y + a.z * a.z + a.w * a.w
             + b.x * b.x + b.y * b.y + b.z * b.z + b.w * b.w;
    float f  = sq / (1.f + sq);
    float rs = sqrtf(sq + 1e-8f);
    float4 o0, o1;
    o0.x = (f * a.x) / rs; o0.y = (f * a.y) / rs;
    o0.z = (f * a.z) / rs; o0.w = (f * a.w) / rs;
    o1.x = (f * b.x) / rs; o1.y = (f * b.y) / rs;
    o1.z = (f * b.z) / rs; o1.w = (f * b.w) / rs;
    float4* po = (float4*)(u + (size_t)cap * 8);
    po[0] = o0; po[1] = o1;
}

// ---------------- x_hat precompute: xh[o][v][b][i] (half-batch) ------------
// xh[o,v,b,i] = sum_d Wr[o,i,v,d] * u[b,i,d];  b in [0,256) local.
__global__ __launch_bounds__(256) void xhat_kernel(
    const float* __restrict__ u,   // [256][512][8] (half-batch base)
    const float* __restrict__ Wr,  // [10][512][16][8]
    float* __restrict__ xh)        // [10][16][256][512]
{
    const int t  = threadIdx.x;
    const int o  = blockIdx.y;
    const int i0 = blockIdx.x << 5;
    const int ii = t & 31;
    const int bs = t >> 5;                 // 0..7

    __shared__ __align__(16) float wsh[32 * 132];  // [ii][v*8+d], stride 132

    // stage Wr[o][i0..i0+32][16][8] = 4096 contiguous floats
    const float* wsrc = Wr + ((size_t)o * 512 + i0) * 128;
    for (int idx = t; idx < 1024; idx += 256) {
        float4 wv = *(const float4*)(wsrc + idx * 4);
        int r = (idx * 4) >> 7;
        int c = (idx * 4) & 127;
        *(float4*)&wsh[r * 132 + c] = wv;
    }
    __syncthreads();

    const int i = i0 + ii;
    const float* wrow = &wsh[ii * 132];

#pragma unroll
    for (int cch = 0; cch < 4; ++cch) {
        float uu[8][8];
#pragma unroll
        for (int l = 0; l < 8; ++l) {
            int b = bs + (cch << 6) + (l << 3);
            float4 u0 = *(const float4*)(u + (size_t)b * 4096 + i * 8);
            float4 u1 = *(const float4*)(u + (size_t)b * 4096 + i * 8 + 4);
            uu[l][0] = u0.x; uu[l][1] = u0.y; uu[l][2] = u0.z; uu[l][3] = u0.w;
            uu[l][4] = u1.x; uu[l][5] = u1.y; uu[l][6] = u1.z; uu[l][7] = u1.w;
        }
#pragma unroll
        for (int v = 0; v < 16; ++v) {
            float4 w0 = *(const float4*)&wrow[v << 3];
            float4 w1 = *(const float4*)&wrow[(v << 3) + 4];
            float acc[8];
#pragma unroll
            for (int l = 0; l < 8; ++l) {
                acc[l] = uu[l][0] * w0.x + uu[l][1] * w0.y + uu[l][2] * w0.z + uu[l][3] * w0.w
                       + uu[l][4] * w1.x + uu[l][5] * w1.y + uu[l][6] * w1.z + uu[l][7] * w1.w;
            }
#pragma unroll
            for (int l = 0; l < 8; ++l) {
                int b = bs + (cch << 6) + (l << 3);
                xh[(((size_t)(o << 4) + v) * 256 + b) * 512 + i] = acc[l];
            }
        }
    }
}

// ---------------- routing from precomputed x_hat (shuffle-free) ------------
__global__ __launch_bounds__(256) void routing2_kernel(
    const float* __restrict__ xh,  // [10][16][256][512]
    float* __restrict__ vout)      // [256][160] (half base)
{
    const int b = blockIdx.x;      // sample within half
    const int t = threadIdx.x;

    __shared__ __align__(16) float b_s[5120];
    __shared__ __align__(16) float c_s[5120];
    __shared__ float s_s[160];
    __shared__ float v_s[160];

    for (int idx = t; idx < 5120; idx += 256) b_s[idx] = 0.f;
    __syncthreads();

    const int o_t = t >> 4;
    const float* xrow = xh + ((size_t)t * 256 + b) * 512;   // valid for t<160

    for (int it = 0; it < 3; ++it) {
        // ---- softmax over o for caps i = t, t+256 ----
        for (int i = t; i < 512; i += 256) {
            float bv[10], mx = -3.4e38f;
#pragma unroll
            for (int o = 0; o < 10; ++o) { bv[o] = b_s[(o << 9) + i]; mx = fmaxf(mx, bv[o]); }
            float sum = 0.f;
#pragma unroll
            for (int o = 0; o < 10; ++o) { bv[o] = expf(bv[o] - mx); sum += bv[o]; }
            float inv = 1.f / sum;
#pragma unroll
            for (int o = 0; o < 10; ++o) c_s[(o << 9) + i] = bv[o] * inv;
        }
        __syncthreads();
        // ---- s[o,v] = sum_i c[o,i] * xh[o,v,b,i] (one thread per (o,v)) ----
        if (t < 160) {
            const float* cp = c_s + (o_t << 9);
            float4 a0 = {0.f, 0.f, 0.f, 0.f};
            float4 a1 = {0.f, 0.f, 0.f, 0.f};
            for (int i = 0; i < 512; i += 8) {
                float4 x0 = *(const float4*)(xrow + i);
                float4 x1 = *(const float4*)(xrow + i + 4);
                float4 c0 = *(const float4*)(cp + i);
                float4 c1 = *(const float4*)(cp + i + 4);
                a0.x = fmaf(x0.x, c0.x, a0.x); a0.y = fmaf(x0.y, c0.y, a0.y);
                a0.z = fmaf(x0.z, c0.z, a0.z); a0.w = fmaf(x0.w, c0.w, a0.w);
                a1.x = fmaf(x1.x, c1.x, a1.x); a1.y = fmaf(x1.y, c1.y, a1.y);
                a1.z = fmaf(x1.z, c1.z, a1.z); a1.w = fmaf(x1.w, c1.w, a1.w);
            }
            s_s[t] = (a0.x + a0.y) + (a0.z + a0.w) + (a1.x + a1.y) + (a1.z + a1.w);
        }
        __syncthreads();
        // ---- squash s -> v (10 threads) ----
        if (t < 10) {
            float tv[16], sq = 0.f;
#pragma unroll
            for (int v = 0; v < 16; ++v) { tv[v] = s_s[(t << 4) + v]; sq = fmaf(tv[v], tv[v], sq); }
            float f  = sq / (1.f + sq);
            float rs = sqrtf(sq + 1e-8f);
#pragma unroll
            for (int v = 0; v < 16; ++v) v_s[(t << 4) + v] = (f * tv[v]) / rs;
        }
        __syncthreads();
        // ---- b[o,i] += v[o,:] . xh[o,:,b,i] ----
        if (it < 2) {
            for (int p = t; p < 5120; p += 256) {
                int o = p >> 9;
                int i = p & 511;
                const float* xp = xh + ((size_t)(o << 4) * 256 + b) * 512 + i;
                float acc = b_s[p];
#pragma unroll
                for (int v = 0; v < 16; ++v)
                    acc = fmaf(v_s[(o << 4) + v], xp[(size_t)v * (256 * 512)], acc);
                b_s[p] = acc;
            }
            __syncthreads();
        }
    }

    for (int idx = t; idx < 160; idx += 256) vout[(size_t)b * 160 + idx] = v_s[idx];
}

// ---------------- FC3: [512,4096] x [10,4096]^T + b -> [512,10] ------------
__global__ __launch_bounds__(256) void fc3_kernel(
    const float* __restrict__ f, const float* __restrict__ w,
    const float* __restrict__ bias, float* __restrict__ out)
{
    const int n = blockIdx.x;
    const int t = threadIdx.x;
    const int lane = t & 63, wv = t >> 6;
    const float* fr = f + (size_t)n * 4096;
    float p[10];
#pragma unroll
    for (int j = 0; j < 10; ++j) p[j] = 0.f;
    for (int k = t; k < 4096; k += 256) {
        float x = fr[k];
#pragma unroll
        for (int j = 0; j < 10; ++j) p[j] = fmaf(x, w[j * 4096 + k], p[j]);
    }
    __shared__ float red[4 * 10];
#pragma unroll
    for (int j = 0; j < 10; ++j) {
        float x = p[j];
        for (int off = 32; off > 0; off >>= 1) x += __shfl_xor(x, off);
        p[j] = x;
    }
    if (lane == 0) {
#pragma unroll
        for (int j = 0; j < 10; ++j) red[wv * 10 + j] = p[j];
    }
    __syncthreads();
    if (t < 10)
        out[(size_t)n * 10 + t] = red[t] + red[10 + t] + red[20 + t] + red[30 + t] + bias[t];
}

// ===========================================================================
extern "C" void kernel_launch(void* const* d_in, const int* in_sizes, int n_in,
                              void* d_out, int out_size, void* d_ws, size_t ws_size,
                              hipStream_t stream)
{
    const float* x   = (const float*)d_in[0];
    const float* w1  = (const float*)d_in[1];
    const float* b1  = (const float*)d_in[2];
    const float* w2  = (const float*)d_in[3];
    const float* b2  = (const float*)d_in[4];
    const float* w3  = (const float*)d_in[5];
    const float* b3  = (const float*)d_in[6];
    const float* w4  = (const float*)d_in[7];
    const float* b4  = (const float*)d_in[8];
    const float* w5  = (const float*)d_in[9];
    const float* b5  = (const float*)d_in[10];
    const float* wp  = (const float*)d_in[11];
    const float* bp  = (const float*)d_in[12];
    const float* Wr  = (const float*)d_in[13];
    const float* fw1 = (const float*)d_in[14];
    const float* fb1 = (const float*)d_in[15];
    const float* fw2 = (const float*)d_in[16];
    const float* fb2 = (const float*)d_in[17];
    const float* fw3 = (const float*)d_in[18];
    const float* fb3 = (const float*)d_in[19];
    float* outp = (float*)d_out;

    char* w = (char*)d_ws;
    // ---- byte offsets (peak ~139.5 MB; round-1 proved >=141.3 MB) ----
    float*    p1   = (float*)(w + 0);              // 38,535,168 B
    float*    a2h  = (float*)(w + 38535168);       // 51,380,224 B (half batch)
    float*    p2   = (float*)(w + 89915392);       // 25,690,112 B
    _Float16* w2h  = (_Float16*)(w + 115605504);
    _Float16* w2l  = (_Float16*)(w + 116047872);
    _Float16* w3h  = (_Float16*)(w + 116490240);
    _Float16* w3l  = (_Float16*)(w + 118259712);
    _Float16* w4h  = (_Float16*)(w + 120029184);
    _Float16* w4l  = (_Float16*)(w + 122683392);
    _Float16* w5h  = (_Float16*)(w + 125337600);
    _Float16* w5l  = (_Float16*)(w + 127107072);
    _Float16* wph  = (_Float16*)(w + 128876544);
    _Float16* wpl  = (_Float16*)(w + 129400832);   // end 129,925,120
    float*    a3   = (float*)(w + 0);
    float*    a4   = (float*)(w + 38535168);
    float*    a5   = (float*)(w + 0);
    float*    p3   = (float*)(w + 25690112);
    float*    pc   = (float*)(w + 38535168);
    float*    u    = (float*)(w + 46923776);       // 8,388,608 B
    float*    vcap = (float*)(w + 55312384);       // 327,680 B
    float*    xh   = (float*)(w + 55640064);       // 83,886,080 B -> end 139,526,144
    float*    f1   = (float*)(w + 55640064);       // after routing, xh is dead
    _Float16* f1h  = (_Float16*)(w + 64028672);
    _Float16* f1l  = (_Float16*)(w + 68222976);
    float*    part = (float*)(w + 72417280);       // 33,554,432 B (4 slices)
    float*    f2   = (float*)(w + 0);

    // ---- pre-split conv weights to f16 hi/lo ----
    split_kernel<<<dim3(864),  dim3(256), 0, stream>>>(w2, w2h, w2l, 221184);
    split_kernel<<<dim3(3456), dim3(256), 0, stream>>>(w3, w3h, w3l, 884736);
    split_kernel<<<dim3(5184), dim3(256), 0, stream>>>(w4, w4h, w4l, 1327104);
    split_kernel<<<dim3(3456), dim3(256), 0, stream>>>(w5, w5h, w5l, 884736);
    split_kernel<<<dim3(1024), dim3(256), 0, stream>>>(wp, wph, wpl, 262144);

    // conv1 + relu + pool1 : x -> p1 [512,96,14,14]
    conv1_pool_kernel<<<dim3(37632), dim3(256), 0, stream>>>(x, w1, b1, p1);

    // conv2 + relu in two batch halves (ws ceiling), each followed by pool2
    conv_f16x3<96, 14, 14, 3, 1, 256, true><<<dim3(392, 2), dim3(256), 0, stream>>>(
        p1, w2h, w2l, b2, a2h, 0);
    maxpool_kernel<256, 256, 14, 14, 7, 7, 3, 2, 1><<<dim3(12544), dim3(256), 0, stream>>>(
        a2h, p2);
    conv_f16x3<96, 14, 14, 3, 1, 256, true><<<dim3(392, 2), dim3(256), 0, stream>>>(
        p1, w2h, w2l, b2, a2h - (size_t)256 * 256 * 196, 256 * 196);
    maxpool_kernel<256, 256, 14, 14, 7, 7, 3, 2, 1><<<dim3(12544), dim3(256), 0, stream>>>(
        a2h, p2 + (size_t)256 * 256 * 49);

    // conv3 + relu : p2 -> a3 [512,384,7,7]
    conv_f16x3<256, 7, 7, 3, 1, 384, true><<<dim3(196, 3), dim3(256), 0, stream>>>(
        p2, w3h, w3l, b3, a3, 0);
    // conv4 + relu : a3 -> a4 [512,384,7,7]
    conv_f16x3<384, 7, 7, 3, 1, 384, true><<<dim3(196, 3), dim3(256), 0, stream>>>(
        a3, w4h, w4l, b4, a4, 0);
    // conv5 + relu : a4 -> a5 [512,256,7,7]
    conv_f16x3<384, 7, 7, 3, 1, 256, true><<<dim3(196, 2), dim3(256), 0, stream>>>(
        a4, w5h, w5l, b5, a5, 0);
    // pool3 : a5 -> p3 [512,256,5,5]
    maxpool_kernel<512, 256, 7, 7, 5, 5, 3, 1, 0><<<dim3(12800), dim3(256), 0, stream>>>(a5, p3);
    // primary caps conv (k2,s1,p0, no relu) : p3 -> pc [512,256,4,4]
    conv_f16x3<256, 5, 5, 2, 0, 256, false><<<dim3(64, 2), dim3(256), 0, stream>>>(
        p3, wph, wpl, bp, pc, 0);
    // squash : pc -> u [512,512,8]
    squash_kernel<<<dim3(1024), dim3(256), 0, stream>>>(pc, u);

    // dynamic routing via precomputed x_hat, two half-batches
    for (int h = 0; h < 2; ++h) {
        const float* uh = u + (size_t)h * 256 * 4096;
        float* vh = vcap + (size_t)h * 256 * 160;
        xhat_kernel<<<dim3(16, 10), dim3(256), 0, stream>>>(uh, Wr, xh);
        routing2_kernel<<<dim3(256), dim3(256), 0, stream>>>(xh, vh);
    }

    // FC1 + relu (fp32, K=160) : vcap -> f1 [512,4096]
    fc_gemm<true><<<dim3(64, 4), dim3(256), 0, stream>>>(vcap, fw1, fb1, f1, 160, 4096);
    // split f1
    split_kernel<<<dim3(8192), dim3(256), 0, stream>>>(f1, f1h, f1l, 2097152);
    // FC2 fp16x3 split-K=4 : f1s, fw2 -> part [4,512,4096]
    fc2_f16x3<<<dim3(32, 4, 4), dim3(256), 0, stream>>>(f1h, f1l, fw2, part, 1024);
    // reduce + bias + relu : part -> f2 [512,4096]
    fc2_reduce_kernel<<<dim3(8192), dim3(256), 0, stream>>>(part, fb2, f2);
    // FC3 : f2 -> out [512,10]
    fc3_kernel<<<dim3(512), dim3(256), 0, stream>>>(f2, fw3, fb3, outp);
}

// Round 6
// 2103.967 us; speedup vs baseline: 2.3032x; 1.1274x over previous
//
#include <hip/hip_runtime.h>
#include <math.h>

// ===========================================================================
// AlexCapsNet forward. Big convs + FC2 via fp16x3-split MFMA (16x16x32_f16).
// a = ah + al/2048 (al stored pre-scaled by 2048 to stay in f16 normal range).
// C = sum ah*bh  +  (sum ah*bl + al*bh) / 2048      (al*bl dropped, ~2^-22)
// Round 6: round-5 n64 conv kernels + FIXED ws layout. Root cause of the r5
// tripwire: p3 (13,107,200 B @25,690,112, ends 38,797,312) overlapped pc
// (@38,535,168) by 256 KiB -> cross-block read/write race in caps conv.
// New layout: pc@0, u@8M, vcap@16M, xh@17M. All pairs audited disjoint.
// Peak ws 129,925,120 B (< proven 139,526,144).
// ===========================================================================

#define BATCH 512

typedef _Float16 half8 __attribute__((ext_vector_type(8)));
typedef float   float4v __attribute__((ext_vector_type(4)));

// ---------------- fp32 -> (hi f16, lo f16*2048) split ----------------------
__global__ __launch_bounds__(256) void split_kernel(
    const float* __restrict__ src, _Float16* __restrict__ hi,
    _Float16* __restrict__ lo, int n)
{
    int idx = blockIdx.x * 256 + threadIdx.x;
    if (idx >= n) return;
    float v = src[idx];
    _Float16 h = (_Float16)v;
    hi[idx] = h;
    lo[idx] = (_Float16)((v - (float)h) * 2048.0f);
}

// ---------------- conv1(1->96,3x3,p1) + relu + maxpool(3,2,1) fused --------
__global__ __launch_bounds__(256) void conv1_pool_kernel(
    const float* __restrict__ x, const float* __restrict__ w1,
    const float* __restrict__ b1, float* __restrict__ out)
{
    int idx = blockIdx.x * 256 + threadIdx.x;       // total = 512*96*14*14
    if (idx >= 512 * 96 * 14 * 14) return;
    int ow = idx % 14; int t1 = idx / 14;
    int oh = t1 % 14;  int t2 = t1 / 14;
    int oc = t2 % 96;  int n  = t2 / 96;
    const float* xi = x + n * 784;
    float w[9];
#pragma unroll
    for (int i = 0; i < 9; ++i) w[i] = w1[oc * 9 + i];
    float bias = b1[oc];
    float best = -3.4e38f;
#pragma unroll
    for (int dy = 0; dy < 3; ++dy) {
        int ph = oh * 2 - 1 + dy;
        if ((unsigned)ph >= 28u) continue;
#pragma unroll
        for (int dx = 0; dx < 3; ++dx) {
            int pw = ow * 2 - 1 + dx;
            if ((unsigned)pw >= 28u) continue;
            float s = bias;
#pragma unroll
            for (int ky = 0; ky < 3; ++ky) {
                int iy = ph - 1 + ky;
                if ((unsigned)iy >= 28u) continue;
#pragma unroll
                for (int kx = 0; kx < 3; ++kx) {
                    int ix = pw - 1 + kx;
                    if ((unsigned)ix >= 28u) continue;
                    s = fmaf(w[ky * 3 + kx], xi[iy * 28 + ix], s);
                }
            }
            s = fmaxf(s, 0.f);
            best = fmaxf(best, s);
        }
    }
    out[idx] = best;
}

// ---------------- generic maxpool (NB = batch count processed) -------------
template<int NB, int C, int H, int W, int OH, int OW, int KS, int STR, int PADP>
__global__ __launch_bounds__(256) void maxpool_kernel(
    const float* __restrict__ in, float* __restrict__ out)
{
    constexpr int TOTAL = NB * C * OH * OW;
    int idx = blockIdx.x * 256 + threadIdx.x;
    if (idx >= TOTAL) return;
    int ow = idx % OW; int t1 = idx / OW;
    int oh = t1 % OH;  int t2 = t1 / OH;
    int c  = t2 % C;   int n  = t2 / C;
    const float* ip = in + (size_t)(n * C + c) * (H * W);
    float best = -3.4e38f;
#pragma unroll
    for (int dy = 0; dy < KS; ++dy) {
        int ih = oh * STR - PADP + dy;
        if ((unsigned)ih >= (unsigned)H) continue;
#pragma unroll
        for (int dx = 0; dx < KS; ++dx) {
            int iw = ow * STR - PADP + dx;
            if ((unsigned)iw >= (unsigned)W) continue;
            best = fmaxf(best, ip[ih * W + iw]);
        }
    }
    out[idx] = best;
}

// ---------------- fp16x3 MFMA implicit-GEMM conv, 128(M)x64(N) tile --------
// M = OC (tile 128), N = batch*OHW (tile 64), K = IC*KH*KH (step 32).
// 4 waves, each computes 64x32 via 4x2 tiles of 16x16x32_f16 MFMA.
// Accumulators: 8+8 float4 = 64 AGPRs -> ~3 blocks/CU resident.
template<int IC, int H, int W, int KH, int PAD, int OC, bool RELU>
__global__ __launch_bounds__(256, 2) void conv_f16x3_n64(
    const float* __restrict__ in, const _Float16* __restrict__ whi,
    const _Float16* __restrict__ wlo, const float* __restrict__ bias,
    float* __restrict__ out, int n_base)
{
    constexpr int OH  = H + 2 * PAD - KH + 1;
    constexpr int OW  = W + 2 * PAD - KH + 1;
    constexpr int OHW = OH * OW;
    constexpr int K   = IC * KH * KH;
    constexpr int KK  = KH * KH;
    constexpr int RS  = 40;   // f16 row stride (32 data + 8 pad)
    static_assert(K % 32 == 0, "K step");

    const int t    = threadIdx.x;
    const int lane = t & 63;
    const int wid  = t >> 6;
    const int wm   = (wid >> 1) << 6;   // 0 / 64
    const int wn   = (wid & 1) << 5;    // 0 / 32
    const int l15  = lane & 15;
    const int quad = lane >> 4;

    __shared__ __align__(16) _Float16 Ah[128 * RS];
    __shared__ __align__(16) _Float16 Al[128 * RS];
    __shared__ __align__(16) _Float16 Bh[64 * RS];
    __shared__ __align__(16) _Float16 Bl[64 * RS];

    const int n0 = blockIdx.x << 6;
    const int m0 = blockIdx.y << 7;

    float4v acc1[8], acc2[8];
#pragma unroll
    for (int i = 0; i < 8; ++i) {
        acc1[i] = (float4v)(0.f);
        acc2[i] = (float4v)(0.f);
    }

    // A staging: thread -> row am, 16 f16 at ak
    const int am = t >> 1;
    const int ak = (t & 1) << 4;
    const _Float16* wh_p = whi + (size_t)(m0 + am) * K + ak;
    const _Float16* wl_p = wlo + (size_t)(m0 + am) * K + ak;

    // B staging: thread -> column n_u, one 8-k unit at k8
    const int n_u  = t & 63;
    const int k8   = ((t >> 6) & 3) << 3;   // 0,8,16,24
    const int gn_u = n_base + n0 + n_u;
    const int b_u  = gn_u / OHW;
    const int p_u  = gn_u - b_u * OHW;
    const int oh_u = p_u / OW;
    const int ow_u = p_u - oh_u * OW;
    const float* inb = in + (size_t)b_u * (IC * H * W);

    for (int kb = 0; kb < K; kb += 32) {
        // ---- stage A (pre-split weights) ----
        *(half8*)&Ah[am * RS + ak]     = *(const half8*)(wh_p + kb);
        *(half8*)&Ah[am * RS + ak + 8] = *(const half8*)(wh_p + kb + 8);
        *(half8*)&Al[am * RS + ak]     = *(const half8*)(wl_p + kb);
        *(half8*)&Al[am * RS + ak + 8] = *(const half8*)(wl_p + kb + 8);
        // ---- stage B (im2col gather fp32 -> split) ----
        {
            int k0 = kb + k8;
            half8 hv, lv;
#pragma unroll
            for (int j = 0; j < 8; ++j) {
                int k  = k0 + j;
                int ic = k / KK;
                int rr = k - ic * KK;
                int kh = rr / KH;
                int kw = rr - kh * KH;
                int ih = oh_u + kh - PAD;
                int iw = ow_u + kw - PAD;
                float v = 0.f;
                if ((unsigned)ih < (unsigned)H && (unsigned)iw < (unsigned)W)
                    v = inb[ic * (H * W) + ih * W + iw];
                _Float16 h = (_Float16)v;
                hv[j] = h;
                lv[j] = (_Float16)((v - (float)h) * 2048.0f);
            }
            *(half8*)&Bh[n_u * RS + k8] = hv;
            *(half8*)&Bl[n_u * RS + k8] = lv;
        }
        __syncthreads();
        // ---- compute ----
        half8 ah[4], al[4], bh[2], bl[2];
#pragma unroll
        for (int i = 0; i < 4; ++i) {
            int ar = wm + i * 16 + l15;
            ah[i] = *(const half8*)&Ah[ar * RS + quad * 8];
            al[i] = *(const half8*)&Al[ar * RS + quad * 8];
        }
#pragma unroll
        for (int i = 0; i < 2; ++i) {
            int br = wn + i * 16 + l15;
            bh[i] = *(const half8*)&Bh[br * RS + quad * 8];
            bl[i] = *(const half8*)&Bl[br * RS + quad * 8];
        }
#pragma unroll
        for (int mi = 0; mi < 4; ++mi)
#pragma unroll
            for (int ni = 0; ni < 2; ++ni) {
                int ix = mi * 2 + ni;
                acc1[ix] = __builtin_amdgcn_mfma_f32_16x16x32_f16(ah[mi], bh[ni], acc1[ix], 0, 0, 0);
                acc2[ix] = __builtin_amdgcn_mfma_f32_16x16x32_f16(ah[mi], bl[ni], acc2[ix], 0, 0, 0);
                acc2[ix] = __builtin_amdgcn_mfma_f32_16x16x32_f16(al[mi], bh[ni], acc2[ix], 0, 0, 0);
            }
        __syncthreads();
    }
    // ---- epilogue: combine, bias(+relu), scatter NCHW ----
#pragma unroll
    for (int mi = 0; mi < 4; ++mi)
#pragma unroll
        for (int ni = 0; ni < 2; ++ni) {
            int ix = mi * 2 + ni;
            int gn = n_base + n0 + wn + ni * 16 + l15;
            int b  = gn / OHW;
            int p  = gn - b * OHW;
#pragma unroll
            for (int r = 0; r < 4; ++r) {
                int m = m0 + wm + mi * 16 + quad * 4 + r;
                float v = acc1[ix][r] + acc2[ix][r] * (1.0f / 2048.0f) + bias[m];
                if (RELU) v = fmaxf(v, 0.f);
                out[((size_t)b * OC + m) * OHW + p] = v;
            }
        }
}

// ---------------- fp16x3 MFMA FC2: [512,4096] x [4096,4096]^T, split-K -----
__global__ __launch_bounds__(256, 2) void fc2_f16x3(
    const _Float16* __restrict__ f1h, const _Float16* __restrict__ f1l,
    const float* __restrict__ Bw, float* __restrict__ part, int kslice)
{
    constexpr int K = 4096, N = 4096;
    constexpr int RS = 40;
    const int t    = threadIdx.x;
    const int lane = t & 63;
    const int wid  = t >> 6;
    const int wm   = (wid >> 1) << 6;
    const int wn   = (wid & 1) << 6;
    const int l15  = lane & 15;
    const int quad = lane >> 4;

    __shared__ __align__(16) _Float16 Ah[128 * RS];
    __shared__ __align__(16) _Float16 Al[128 * RS];
    __shared__ __align__(16) _Float16 Bh[128 * RS];
    __shared__ __align__(16) _Float16 Bl[128 * RS];

    const int n0 = blockIdx.x << 7;
    const int m0 = blockIdx.y << 7;
    const int kbeg = blockIdx.z * kslice;

    float4v acc1[16], acc2[16];
#pragma unroll
    for (int i = 0; i < 16; ++i) {
        acc1[i] = (float4v)(0.f);
        acc2[i] = (float4v)(0.f);
    }

    const int am = t >> 1;
    const int ak = (t & 1) << 4;
    const _Float16* ah_p = f1h + (size_t)(m0 + am) * K + kbeg + ak;
    const _Float16* al_p = f1l + (size_t)(m0 + am) * K + kbeg + ak;
    const float*    bw_p = Bw  + (size_t)(n0 + am) * K + kbeg + ak;

    for (int kb = 0; kb < kslice; kb += 32) {
        *(half8*)&Ah[am * RS + ak]     = *(const half8*)(ah_p + kb);
        *(half8*)&Ah[am * RS + ak + 8] = *(const half8*)(ah_p + kb + 8);
        *(half8*)&Al[am * RS + ak]     = *(const half8*)(al_p + kb);
        *(half8*)&Al[am * RS + ak + 8] = *(const half8*)(al_p + kb + 8);
        {
            half8 hv0, lv0, hv1, lv1;
#pragma unroll
            for (int j = 0; j < 8; ++j) {
                float v = bw_p[kb + j];
                _Float16 h = (_Float16)v;
                hv0[j] = h;
                lv0[j] = (_Float16)((v - (float)h) * 2048.0f);
            }
#pragma unroll
            for (int j = 0; j < 8; ++j) {
                float v = bw_p[kb + 8 + j];
                _Float16 h = (_Float16)v;
                hv1[j] = h;
                lv1[j] = (_Float16)((v - (float)h) * 2048.0f);
            }
            *(half8*)&Bh[am * RS + ak]     = hv0;
            *(half8*)&Bh[am * RS + ak + 8] = hv1;
            *(half8*)&Bl[am * RS + ak]     = lv0;
            *(half8*)&Bl[am * RS + ak + 8] = lv1;
        }
        __syncthreads();
        half8 ah[4], al[4], bh[4], bl[4];
#pragma unroll
        for (int i = 0; i < 4; ++i) {
            int ar = wm + i * 16 + l15;
            int br = wn + i * 16 + l15;
            ah[i] = *(const half8*)&Ah[ar * RS + quad * 8];
            al[i] = *(const half8*)&Al[ar * RS + quad * 8];
            bh[i] = *(const half8*)&Bh[br * RS + quad * 8];
            bl[i] = *(const half8*)&Bl[br * RS + quad * 8];
        }
#pragma unroll
        for (int mi = 0; mi < 4; ++mi)
#pragma unroll
            for (int ni = 0; ni < 4; ++ni) {
                int ix = mi * 4 + ni;
                acc1[ix] = __builtin_amdgcn_mfma_f32_16x16x32_f16(ah[mi], bh[ni], acc1[ix], 0, 0, 0);
                acc2[ix] = __builtin_amdgcn_mfma_f32_16x16x32_f16(ah[mi], bl[ni], acc2[ix], 0, 0, 0);
                acc2[ix] = __builtin_amdgcn_mfma_f32_16x16x32_f16(al[mi], bh[ni], acc2[ix], 0, 0, 0);
            }
        __syncthreads();
    }
    float* po = part + (size_t)blockIdx.z * (512 * 4096);
#pragma unroll
    for (int mi = 0; mi < 4; ++mi)
#pragma unroll
        for (int ni = 0; ni < 4; ++ni) {
            int ix = mi * 4 + ni;
            int gn = n0 + wn + ni * 16 + l15;
#pragma unroll
            for (int r = 0; r < 4; ++r) {
                int m = m0 + wm + mi * 16 + quad * 4 + r;
                po[(size_t)m * N + gn] = acc1[ix][r] + acc2[ix][r] * (1.0f / 2048.0f);
            }
        }
}

// ---------------- split-K reduce for FC2 (+bias+relu) ----------------------
__global__ __launch_bounds__(256) void fc2_reduce_kernel(
    const float* __restrict__ part, const float* __restrict__ bias,
    float* __restrict__ out)
{
    int idx = blockIdx.x * 256 + threadIdx.x;   // < 512*4096
    if (idx >= 512 * 4096) return;
    const size_t MN = (size_t)512 * 4096;
    float s = 0.f;
#pragma unroll
    for (int zz = 0; zz < 4; ++zz) s += part[zz * MN + idx];
    s += bias[idx & 4095];
    out[idx] = fmaxf(s, 0.f);
}

// ---------------- FC1 fp32 GEMM (K=160, small) -----------------------------
template<bool RELU>
__global__ __launch_bounds__(256) void fc_gemm(
    const float* __restrict__ A, const float* __restrict__ Bw,
    const float* __restrict__ bias, float* __restrict__ out,
    int K, int N)
{
    const int t  = threadIdx.x;
    const int j0 = blockIdx.x << 6;
    const int m0 = blockIdx.y << 7;

    __shared__ __align__(16) float As[16 * 132];
    __shared__ __align__(16) float Bs[16 * 64];

    float acc[8][4];
#pragma unroll
    for (int a = 0; a < 8; ++a)
#pragma unroll
        for (int b = 0; b < 4; ++b) acc[a][b] = 0.f;

    const int a_m  = t >> 2;
    const int a_k  = (t & 3) << 2;
    const int b_j  = t & 63;
    const int b_k0 = (t >> 6) << 2;
    const int ms = (t >> 4) << 3;
    const int js = (t & 15) << 2;

    for (int kb0 = 0; kb0 < K; kb0 += 16) {
#pragma unroll
        for (int r = 0; r < 2; ++r) {
            int m = m0 + a_m + (r << 6);
            float4 av = *(const float4*)(A + (size_t)m * K + kb0 + a_k);
            As[(a_k + 0) * 132 + a_m + (r << 6)] = av.x;
            As[(a_k + 1) * 132 + a_m + (r << 6)] = av.y;
            As[(a_k + 2) * 132 + a_m + (r << 6)] = av.z;
            As[(a_k + 3) * 132 + a_m + (r << 6)] = av.w;
        }
        {
            float4 bv = *(const float4*)(Bw + (size_t)(j0 + b_j) * K + kb0 + b_k0);
            Bs[(b_k0 + 0) * 64 + b_j] = bv.x;
            Bs[(b_k0 + 1) * 64 + b_j] = bv.y;
            Bs[(b_k0 + 2) * 64 + b_j] = bv.z;
            Bs[(b_k0 + 3) * 64 + b_j] = bv.w;
        }
        __syncthreads();
#pragma unroll
        for (int kk = 0; kk < 16; ++kk) {
            float4 A0 = *(const float4*)&As[kk * 132 + ms];
            float4 A1 = *(const float4*)&As[kk * 132 + ms + 4];
            float4 B0 = *(const float4*)&Bs[(kk << 6) + js];
            float av[8] = {A0.x, A0.y, A0.z, A0.w, A1.x, A1.y, A1.z, A1.w};
            float bv[4] = {B0.x, B0.y, B0.z, B0.w};
#pragma unroll
            for (int mm = 0; mm < 8; ++mm)
#pragma unroll
                for (int jj = 0; jj < 4; ++jj)
                    acc[mm][jj] = fmaf(av[mm], bv[jj], acc[mm][jj]);
        }
        __syncthreads();
    }
    float4 b4 = *(const float4*)(bias + j0 + js);
#pragma unroll
    for (int mm = 0; mm < 8; ++mm) {
        float4 o;
        o.x = acc[mm][0] + b4.x;
        o.y = acc[mm][1] + b4.y;
        o.z = acc[mm][2] + b4.z;
        o.w = acc[mm][3] + b4.w;
        if (RELU) {
            o.x = fmaxf(o.x, 0.f); o.y = fmaxf(o.y, 0.f);
            o.z = fmaxf(o.z, 0.f); o.w = fmaxf(o.w, 0.f);
        }
        *(float4*)(out + (size_t)(m0 + ms + mm) * N + j0 + js) = o;
    }
}

// ---------------- squash of primary caps -----------------------------------
__global__ __launch_bounds__(256) void squash_kernel(
    const float* __restrict__ p, float* __restrict__ u)
{
    int cap = blockIdx.x * 256 + threadIdx.x;   // < 512*512
    if (cap >= 512 * 512) return;
    const float4* pi = (const float4*)(p + (size_t)cap * 8);
    float4 a = pi[0], b = pi[1];
    float sq = a.x * a.x + a.y * a.y + a.z * a.z + a.w * a.w
             + b.x * b.x + b.y * b.y + b.z * b.z + b.w * b.w;
    float f  = sq / (1.f + sq);
    float rs = sqrtf(sq + 1e-8f);
    float4 o0, o1;
    o0.x = (f * a.x) / rs; o0.y = (f * a.y) / rs;
    o0.z = (f * a.z) / rs; o0.w = (f * a.w) / rs;
    o1.x = (f * b.x) / rs; o1.y = (f * b.y) / rs;
    o1.z = (f * b.z) / rs; o1.w = (f * b.w) / rs;
    float4* po = (float4*)(u + (size_t)cap * 8);
    po[0] = o0; po[1] = o1;
}

// ---------------- x_hat precompute: xh[o][v][b][i] (half-batch) ------------
__global__ __launch_bounds__(256) void xhat_kernel(
    const float* __restrict__ u,   // [256][512][8] (half-batch base)
    const float* __restrict__ Wr,  // [10][512][16][8]
    float* __restrict__ xh)        // [10][16][256][512]
{
    const int t  = threadIdx.x;
    const int o  = blockIdx.y;
    const int i0 = blockIdx.x << 5;
    const int ii = t & 31;
    const int bs = t >> 5;                 // 0..7

    __shared__ __align__(16) float wsh[32 * 132];

    const float* wsrc = Wr + ((size_t)o * 512 + i0) * 128;
    for (int idx = t; idx < 1024; idx += 256) {
        float4 wv = *(const float4*)(wsrc + idx * 4);
        int r = (idx * 4) >> 7;
        int c = (idx * 4) & 127;
        *(float4*)&wsh[r * 132 + c] = wv;
    }
    __syncthreads();

    const int i = i0 + ii;
    const float* wrow = &wsh[ii * 132];

#pragma unroll
    for (int cch = 0; cch < 4; ++cch) {
        float uu[8][8];
#pragma unroll
        for (int l = 0; l < 8; ++l) {
            int b = bs + (cch << 6) + (l << 3);
            float4 u0 = *(const float4*)(u + (size_t)b * 4096 + i * 8);
            float4 u1 = *(const float4*)(u + (size_t)b * 4096 + i * 8 + 4);
            uu[l][0] = u0.x; uu[l][1] = u0.y; uu[l][2] = u0.z; uu[l][3] = u0.w;
            uu[l][4] = u1.x; uu[l][5] = u1.y; uu[l][6] = u1.z; uu[l][7] = u1.w;
        }
#pragma unroll
        for (int v = 0; v < 16; ++v) {
            float4 w0 = *(const float4*)&wrow[v << 3];
            float4 w1 = *(const float4*)&wrow[(v << 3) + 4];
            float acc[8];
#pragma unroll
            for (int l = 0; l < 8; ++l) {
                acc[l] = uu[l][0] * w0.x + uu[l][1] * w0.y + uu[l][2] * w0.z + uu[l][3] * w0.w
                       + uu[l][4] * w1.x + uu[l][5] * w1.y + uu[l][6] * w1.z + uu[l][7] * w1.w;
            }
#pragma unroll
            for (int l = 0; l < 8; ++l) {
                int b = bs + (cch << 6) + (l << 3);
                xh[(((size_t)(o << 4) + v) * 256 + b) * 512 + i] = acc[l];
            }
        }
    }
}

// ---------------- routing from precomputed x_hat (shuffle-free) ------------
__global__ __launch_bounds__(256) void routing2_kernel(
    const float* __restrict__ xh,  // [10][16][256][512]
    float* __restrict__ vout)      // [256][160] (half base)
{
    const int b = blockIdx.x;
    const int t = threadIdx.x;

    __shared__ __align__(16) float b_s[5120];
    __shared__ __align__(16) float c_s[5120];
    __shared__ float s_s[160];
    __shared__ float v_s[160];

    for (int idx = t; idx < 5120; idx += 256) b_s[idx] = 0.f;
    __syncthreads();

    const int o_t = t >> 4;
    const float* xrow = xh + ((size_t)t * 256 + b) * 512;

    for (int it = 0; it < 3; ++it) {
        for (int i = t; i < 512; i += 256) {
            float bv[10], mx = -3.4e38f;
#pragma unroll
            for (int o = 0; o < 10; ++o) { bv[o] = b_s[(o << 9) + i]; mx = fmaxf(mx, bv[o]); }
            float sum = 0.f;
#pragma unroll
            for (int o = 0; o < 10; ++o) { bv[o] = expf(bv[o] - mx); sum += bv[o]; }
            float inv = 1.f / sum;
#pragma unroll
            for (int o = 0; o < 10; ++o) c_s[(o << 9) + i] = bv[o] * inv;
        }
        __syncthreads();
        if (t < 160) {
            const float* cp = c_s + (o_t << 9);
            float4 a0 = {0.f, 0.f, 0.f, 0.f};
            float4 a1 = {0.f, 0.f, 0.f, 0.f};
            for (int i = 0; i < 512; i += 8) {
                float4 x0 = *(const float4*)(xrow + i);
                float4 x1 = *(const float4*)(xrow + i + 4);
                float4 c0 = *(const float4*)(cp + i);
                float4 c1 = *(const float4*)(cp + i + 4);
                a0.x = fmaf(x0.x, c0.x, a0.x); a0.y = fmaf(x0.y, c0.y, a0.y);
                a0.z = fmaf(x0.z, c0.z, a0.z); a0.w = fmaf(x0.w, c0.w, a0.w);
                a1.x = fmaf(x1.x, c1.x, a1.x); a1.y = fmaf(x1.y, c1.y, a1.y);
                a1.z = fmaf(x1.z, c1.z, a1.z); a1.w = fmaf(x1.w, c1.w, a1.w);
            }
            s_s[t] = (a0.x + a0.y) + (a0.z + a0.w) + (a1.x + a1.y) + (a1.z + a1.w);
        }
        __syncthreads();
        if (t < 10) {
            float tv[16], sq = 0.f;
#pragma unroll
            for (int v = 0; v < 16; ++v) { tv[v] = s_s[(t << 4) + v]; sq = fmaf(tv[v], tv[v], sq); }
            float f  = sq / (1.f + sq);
            float rs = sqrtf(sq + 1e-8f);
#pragma unroll
            for (int v = 0; v < 16; ++v) v_s[(t << 4) + v] = (f * tv[v]) / rs;
        }
        __syncthreads();
        if (it < 2) {
            for (int p = t; p < 5120; p += 256) {
                int o = p >> 9;
                int i = p & 511;
                const float* xp = xh + ((size_t)(o << 4) * 256 + b) * 512 + i;
                float acc = b_s[p];
#pragma unroll
                for (int v = 0; v < 16; ++v)
                    acc = fmaf(v_s[(o << 4) + v], xp[(size_t)v * (256 * 512)], acc);
                b_s[p] = acc;
            }
            __syncthreads();
        }
    }

    for (int idx = t; idx < 160; idx += 256) vout[(size_t)b * 160 + idx] = v_s[idx];
}

// ---------------- FC3: [512,4096] x [10,4096]^T + b -> [512,10] ------------
__global__ __launch_bounds__(256) void fc3_kernel(
    const float* __restrict__ f, const float* __restrict__ w,
    const float* __restrict__ bias, float* __restrict__ out)
{
    const int n = blockIdx.x;
    const int t = threadIdx.x;
    const int lane = t & 63, wv = t >> 6;
    const float* fr = f + (size_t)n * 4096;
    float p[10];
#pragma unroll
    for (int j = 0; j < 10; ++j) p[j] = 0.f;
    for (int k = t; k < 4096; k += 256) {
        float x = fr[k];
#pragma unroll
        for (int j = 0; j < 10; ++j) p[j] = fmaf(x, w[j * 4096 + k], p[j]);
    }
    __shared__ float red[4 * 10];
#pragma unroll
    for (int j = 0; j < 10; ++j) {
        float x = p[j];
        for (int off = 32; off > 0; off >>= 1) x += __shfl_xor(x, off);
        p[j] = x;
    }
    if (lane == 0) {
#pragma unroll
        for (int j = 0; j < 10; ++j) red[wv * 10 + j] = p[j];
    }
    __syncthreads();
    if (t < 10)
        out[(size_t)n * 10 + t] = red[t] + red[10 + t] + red[20 + t] + red[30 + t] + bias[t];
}

// ===========================================================================
extern "C" void kernel_launch(void* const* d_in, const int* in_sizes, int n_in,
                              void* d_out, int out_size, void* d_ws, size_t ws_size,
                              hipStream_t stream)
{
    const float* x   = (const float*)d_in[0];
    const float* w1  = (const float*)d_in[1];
    const float* b1  = (const float*)d_in[2];
    const float* w2  = (const float*)d_in[3];
    const float* b2  = (const float*)d_in[4];
    const float* w3  = (const float*)d_in[5];
    const float* b3  = (const float*)d_in[6];
    const float* w4  = (const float*)d_in[7];
    const float* b4  = (const float*)d_in[8];
    const float* w5  = (const float*)d_in[9];
    const float* b5  = (const float*)d_in[10];
    const float* wp  = (const float*)d_in[11];
    const float* bp  = (const float*)d_in[12];
    const float* Wr  = (const float*)d_in[13];
    const float* fw1 = (const float*)d_in[14];
    const float* fb1 = (const float*)d_in[15];
    const float* fw2 = (const float*)d_in[16];
    const float* fb2 = (const float*)d_in[17];
    const float* fw3 = (const float*)d_in[18];
    const float* fb3 = (const float*)d_in[19];
    float* outp = (float*)d_out;

    char* w = (char*)d_ws;
    // ---- static weight-split region (lives at 115,605,504..129,925,120) ----
    _Float16* w2h  = (_Float16*)(w + 115605504);
    _Float16* w2l  = (_Float16*)(w + 116047872);
    _Float16* w3h  = (_Float16*)(w + 116490240);
    _Float16* w3l  = (_Float16*)(w + 118259712);
    _Float16* w4h  = (_Float16*)(w + 120029184);
    _Float16* w4l  = (_Float16*)(w + 122683392);
    _Float16* w5h  = (_Float16*)(w + 125337600);
    _Float16* w5l  = (_Float16*)(w + 127107072);
    _Float16* wph  = (_Float16*)(w + 128876544);
    _Float16* wpl  = (_Float16*)(w + 129400832);   // end 129,925,120

    // ---- dynamic region timeline (all producer/consumer pairs disjoint) ----
    float*    p1   = (float*)(w + 0);              // 38,535,168 B
    float*    a2h  = (float*)(w + 38535168);       // 51,380,224 B (half batch)
    float*    p2   = (float*)(w + 89915392);       // 25,690,112 B, ends 115,605,504
    float*    a3   = (float*)(w + 0);              // 38,535,168 B
    float*    a4   = (float*)(w + 38535168);       // 38,535,168 B, ends 77,070,336
    float*    a5   = (float*)(w + 0);              // 25,690,112 B
    float*    p3   = (float*)(w + 25690112);       // 13,107,200 B, ends 38,797,312
    float*    pc   = (float*)(w + 0);              //  8,388,608 B   (r5 fix: was overlapping p3!)
    float*    u    = (float*)(w + 8388608);        //  8,388,608 B, ends 16,777,216
    float*    vcap = (float*)(w + 16777216);       //    327,680 B, ends 17,104,896
    float*    xh   = (float*)(w + 17104896);       // 83,886,080 B, ends 100,990,976
    float*    f1   = (float*)(w + 17104896);       // xh dead after routing
    _Float16* f1h  = (_Float16*)(w + 25493504);
    _Float16* f1l  = (_Float16*)(w + 29687808);
    float*    part = (float*)(w + 33882112);       // 33,554,432 B (4 slices), ends 67,436,544
    float*    f2   = (float*)(w + 67436544);       //  8,388,608 B, ends 75,825,152

    // ---- pre-split conv weights to f16 hi/lo ----
    split_kernel<<<dim3(864),  dim3(256), 0, stream>>>(w2, w2h, w2l, 221184);
    split_kernel<<<dim3(3456), dim3(256), 0, stream>>>(w3, w3h, w3l, 884736);
    split_kernel<<<dim3(5184), dim3(256), 0, stream>>>(w4, w4h, w4l, 1327104);
    split_kernel<<<dim3(3456), dim3(256), 0, stream>>>(w5, w5h, w5l, 884736);
    split_kernel<<<dim3(1024), dim3(256), 0, stream>>>(wp, wph, wpl, 262144);

    // conv1 + relu + pool1 : x -> p1 [512,96,14,14]
    conv1_pool_kernel<<<dim3(37632), dim3(256), 0, stream>>>(x, w1, b1, p1);

    // conv2 + relu, two batch halves (ws ceiling), each followed by pool2
    conv_f16x3_n64<96, 14, 14, 3, 1, 256, true><<<dim3(784, 2), dim3(256), 0, stream>>>(
        p1, w2h, w2l, b2, a2h, 0);
    maxpool_kernel<256, 256, 14, 14, 7, 7, 3, 2, 1><<<dim3(12544), dim3(256), 0, stream>>>(
        a2h, p2);
    conv_f16x3_n64<96, 14, 14, 3, 1, 256, true><<<dim3(784, 2), dim3(256), 0, stream>>>(
        p1, w2h, w2l, b2, a2h - (size_t)256 * 256 * 196, 256 * 196);
    maxpool_kernel<256, 256, 14, 14, 7, 7, 3, 2, 1><<<dim3(12544), dim3(256), 0, stream>>>(
        a2h, p2 + (size_t)256 * 256 * 49);

    // conv3 + relu : p2 -> a3 [512,384,7,7]
    conv_f16x3_n64<256, 7, 7, 3, 1, 384, true><<<dim3(392, 3), dim3(256), 0, stream>>>(
        p2, w3h, w3l, b3, a3, 0);
    // conv4 + relu : a3 -> a4 [512,384,7,7]
    conv_f16x3_n64<384, 7, 7, 3, 1, 384, true><<<dim3(392, 3), dim3(256), 0, stream>>>(
        a3, w4h, w4l, b4, a4, 0);
    // conv5 + relu : a4 -> a5 [512,256,7,7]
    conv_f16x3_n64<384, 7, 7, 3, 1, 256, true><<<dim3(392, 2), dim3(256), 0, stream>>>(
        a4, w5h, w5l, b5, a5, 0);
    // pool3 : a5 -> p3 [512,256,5,5]
    maxpool_kernel<512, 256, 7, 7, 5, 5, 3, 1, 0><<<dim3(12800), dim3(256), 0, stream>>>(a5, p3);
    // primary caps conv (k2,s1,p0, no relu) : p3 -> pc [512,256,4,4]
    conv_f16x3_n64<256, 5, 5, 2, 0, 256, false><<<dim3(128, 2), dim3(256), 0, stream>>>(
        p3, wph, wpl, bp, pc, 0);
    // squash : pc -> u [512,512,8]
    squash_kernel<<<dim3(1024), dim3(256), 0, stream>>>(pc, u);

    // dynamic routing via precomputed x_hat, two half-batches
    for (int h = 0; h < 2; ++h) {
        const float* uh = u + (size_t)h * 256 * 4096;
        float* vh = vcap + (size_t)h * 256 * 160;
        xhat_kernel<<<dim3(16, 10), dim3(256), 0, stream>>>(uh, Wr, xh);
        routing2_kernel<<<dim3(256), dim3(256), 0, stream>>>(xh, vh);
    }

    // FC1 + relu (fp32, K=160) : vcap -> f1 [512,4096]
    fc_gemm<true><<<dim3(64, 4), dim3(256), 0, stream>>>(vcap, fw1, fb1, f1, 160, 4096);
    // split f1
    split_kernel<<<dim3(8192), dim3(256), 0, stream>>>(f1, f1h, f1l, 2097152);
    // FC2 fp16x3 split-K=4 : f1s, fw2 -> part [4,512,4096]
    fc2_f16x3<<<dim3(32, 4, 4), dim3(256), 0, stream>>>(f1h, f1l, fw2, part, 1024);
    // reduce + bias + relu : part -> f2 [512,4096]
    fc2_reduce_kernel<<<dim3(8192), dim3(256), 0, stream>>>(part, fb2, f2);
    // FC3 : f2 -> out [512,10]
    fc3_kernel<<<dim3(512), dim3(256), 0, stream>>>(f2, fw3, fb3, outp);
}